// Round 1
// 952.013 us; speedup vs baseline: 1.0551x; 1.0551x over previous
//
#include <hip/hip_runtime.h>
#include <cstdint>

// ---------------------------------------------------------------------------
// MaskedTransformerDecoderLayer on MI355X.
// All GEMMs: bf16-MFMA tiles (16x16x32), fp32 accumulate, double-buffered LDS.
// D=1024, NHEAD=8, NQ=256, B=8, S=4096, FF=4096.
// This round: KV-projection GEMM (32768x2048x1024) moved to a 256^2-tile
// 8-wave deep-pipelined kernel (4-deep LDS buffering, counted vmcnt, phase
// barriers, st-swizzled LDS, setprio around MFMA clusters).
// ---------------------------------------------------------------------------

typedef __attribute__((ext_vector_type(8))) __bf16 bf16x8;
typedef __attribute__((ext_vector_type(4))) float f32x4;
typedef __attribute__((ext_vector_type(8))) unsigned short ushort8;
typedef __attribute__((ext_vector_type(4))) unsigned short ushort4v;

__device__ __forceinline__ unsigned short f2bf(float f) {
  return __builtin_bit_cast(unsigned short, (__bf16)f);
}

// ---------------- cast fp32 -> bf16 (8 elems/thread) ----------------
__global__ __launch_bounds__(256) void cast_bf16_kernel(const float* __restrict__ in,
                                                        unsigned short* __restrict__ out,
                                                        int n8) {
  int i = blockIdx.x * 256 + threadIdx.x;
  if (i >= n8) return;
  const float4* p = (const float4*)in + (size_t)i * 2;
  float4 a = p[0], b = p[1];
  ushort8 o;
  o[0] = f2bf(a.x); o[1] = f2bf(a.y); o[2] = f2bf(a.z); o[3] = f2bf(a.w);
  o[4] = f2bf(b.x); o[5] = f2bf(b.y); o[6] = f2bf(b.z); o[7] = f2bf(b.w);
  ((ushort8*)out)[i] = o;
}

// ---------------- fused multi-tensor cast (dst regions contiguous) ----------
struct CastSegs {
  const float* src[9];
  int cum[10];  // cumulative n8 counts
};
__global__ __launch_bounds__(256) void cast_multi_kernel(CastSegs cs,
                                                         unsigned short* __restrict__ out) {
  int i = blockIdx.x * 256 + threadIdx.x;
  if (i >= cs.cum[9]) return;
  int s = 0;
  while (i >= cs.cum[s + 1]) s++;
  const float4* p = (const float4*)cs.src[s] + (size_t)(i - cs.cum[s]) * 2;
  float4 a = p[0], b = p[1];
  ushort8 o;
  o[0] = f2bf(a.x); o[1] = f2bf(a.y); o[2] = f2bf(a.z); o[3] = f2bf(a.w);
  o[4] = f2bf(b.x); o[5] = f2bf(b.y); o[6] = f2bf(b.z); o[7] = f2bf(b.w);
  ((ushort8*)out)[i] = o;
}

__global__ __launch_bounds__(256) void bias_concat_kernel(const float* __restrict__ a,
                                                          const float* __restrict__ b,
                                                          float* __restrict__ o) {
  int i = blockIdx.x * 256 + threadIdx.x;
  o[i] = i < 1024 ? a[i] : b[i - 1024];
}

// ---------------- LayerNorm over D=1024, bf16 out ----------------
__global__ __launch_bounds__(256) void ln_bf16_kernel(const float* __restrict__ x,
                                                      const float* __restrict__ g,
                                                      const float* __restrict__ b,
                                                      unsigned short* __restrict__ out) {
  int row = blockIdx.x, tid = threadIdx.x;
  const float4* xr = (const float4*)(x + (size_t)row * 1024);
  float4 v = xr[tid];
  float s = v.x + v.y + v.z + v.w;
  float sq = v.x * v.x + v.y * v.y + v.z * v.z + v.w * v.w;
#pragma unroll
  for (int o = 32; o > 0; o >>= 1) { s += __shfl_xor(s, o); sq += __shfl_xor(sq, o); }
  __shared__ float red[8];
  int wave = tid >> 6, lane = tid & 63;
  if (lane == 0) { red[wave] = s; red[4 + wave] = sq; }
  __syncthreads();
  float ts = red[0] + red[1] + red[2] + red[3];
  float tq = red[4] + red[5] + red[6] + red[7];
  float mean = ts * (1.f / 1024.f);
  float var = tq * (1.f / 1024.f) - mean * mean;
  float rstd = rsqrtf(var + 1e-5f);
  float4 gv = ((const float4*)g)[tid];
  float4 bv = ((const float4*)b)[tid];
  ushort4v o;
  o[0] = f2bf((v.x - mean) * rstd * gv.x + bv.x);
  o[1] = f2bf((v.y - mean) * rstd * gv.y + bv.y);
  o[2] = f2bf((v.z - mean) * rstd * gv.z + bv.z);
  o[3] = f2bf((v.w - mean) * rstd * gv.w + bv.w);
  ((ushort4v*)(out + (size_t)row * 1024))[tid] = o;
}

// ---------------- rowwise softmax, optional +log(mask+1e-6), bf16 out -------
template <bool MASK, int CNT>
__global__ __launch_bounds__(256) void softmax_bf16_kernel(const float* __restrict__ sc,
                                                           const float* __restrict__ pm,
                                                           unsigned short* __restrict__ out,
                                                           float scale) {
  const int L = CNT * 256;
  int row = blockIdx.x, tid = threadIdx.x;
  const float* sr = sc + (size_t)row * L;
  float vals[CNT];
  float mx = -1e30f;
#pragma unroll
  for (int i = 0; i < CNT; i++) {
    int idx = tid + (i << 8);
    float v = sr[idx] * scale;
    if (MASK) v += __logf(pm[(size_t)row * L + idx] + 1e-6f);
    vals[i] = v;
    mx = fmaxf(mx, v);
  }
#pragma unroll
  for (int o = 32; o > 0; o >>= 1) mx = fmaxf(mx, __shfl_xor(mx, o));
  __shared__ float red[8];
  int wave = tid >> 6, lane = tid & 63;
  if (lane == 0) red[wave] = mx;
  __syncthreads();
  mx = fmaxf(fmaxf(red[0], red[1]), fmaxf(red[2], red[3]));
  float sum = 0.f;
#pragma unroll
  for (int i = 0; i < CNT; i++) { vals[i] = __expf(vals[i] - mx); sum += vals[i]; }
#pragma unroll
  for (int o = 32; o > 0; o >>= 1) sum += __shfl_xor(sum, o);
  if (lane == 0) red[4 + wave] = sum;
  __syncthreads();
  float rs = 1.f / (red[4] + red[5] + red[6] + red[7]);
#pragma unroll
  for (int i = 0; i < CNT; i++)
    out[(size_t)row * L + tid + (i << 8)] = f2bf(vals[i] * rs);
}

// ---------------- batched bf16 transpose (32x32 tiles via LDS) ----------------
__global__ __launch_bounds__(256) void transpose_bf16_kernel(
    const unsigned short* __restrict__ in, unsigned short* __restrict__ out,
    long in_off, int in_rs, long in_hi, long in_lo, int zdiv,
    long out_off, int out_rs, long out_hi, long out_lo) {
  __shared__ unsigned short t[32][33];
  int z = blockIdx.z;
  int zh = z / zdiv, zl = z % zdiv;
  const unsigned short* ib = in + in_off + (long)zh * in_hi + (long)zl * in_lo;
  unsigned short* ob = out + out_off + (long)zh * out_hi + (long)zl * out_lo;
  int i0 = blockIdx.x * 32;
  int j0 = blockIdx.y * 32;
  int tx = threadIdx.x & 31, ty = threadIdx.x >> 5;
#pragma unroll
  for (int r = ty; r < 32; r += 8) t[r][tx] = ib[(long)(j0 + r) * in_rs + i0 + tx];
  __syncthreads();
#pragma unroll
  for (int r = ty; r < 32; r += 8) ob[(long)(i0 + r) * out_rs + j0 + tx] = t[tx][r];
}

// ---------------- batched NT GEMM: C[m,n] = sum_k A[m,k]*B[n,k] ----------------
// Tile TM x 128, BK=32, 4 waves (2x2), DOUBLE-BUFFERED LDS.
template <int TM, bool AF32, bool BIAS, int ACT, bool RES, bool OUTF, bool OUTB, bool KVSPLIT>
__global__ __launch_bounds__(256) void gemm_nt_kernel(
    const void* __restrict__ Av, long a_off, int lda, long a_hi, long a_lo,
    const unsigned short* __restrict__ B, long b_off, int ldb, long b_hi, long b_lo,
    const float* __restrict__ bias, const float* __restrict__ Res,
    float* __restrict__ Cf, long c_off, int ldc, long c_hi, long c_lo,
    unsigned short* __restrict__ Cb, long cb_off, int ldcb, long cb_hi, long cb_lo,
    int K, int zdiv) {
  constexpr int MI = TM / 32;
  __shared__ unsigned short As[2 * TM * 32];
  __shared__ unsigned short Bs[2 * 128 * 32];
  int tid = threadIdx.x;
  int wave = tid >> 6, lane = tid & 63;
  int z = blockIdx.z, zh = z / zdiv, zl = z % zdiv;
  long m0 = (long)blockIdx.x * TM, n0 = (long)blockIdx.y * 128;

  const unsigned short* Bb = B + b_off + zh * b_hi + zl * b_lo + n0 * ldb;
  const unsigned short* Ab16 = nullptr;
  const float* Abf = nullptr;
  if constexpr (AF32)
    Abf = (const float*)Av + a_off + zh * a_hi + zl * a_lo + m0 * lda;
  else
    Ab16 = (const unsigned short*)Av + a_off + zh * a_hi + zl * a_lo + m0 * lda;

  int srow = lane >> 2;
  int scol = (lane & 3) * 8;
  int wm = (wave >> 1) * (TM / 2), wn = (wave & 1) * 64;
  int fr = lane & 15;
  int ko = (lane >> 4) * 8;

  f32x4 acc[MI][4] = {};

  auto stage = [&](int buf, int k0) {
    unsigned short* Ad = As + buf * (TM * 32);
    unsigned short* Bd = Bs + buf * (128 * 32);
    if constexpr (AF32) {
      int row = tid >> 1;
      int cs = (tid & 1) * 16;
      const float* ap = Abf + (long)row * lda + k0 + cs;
      float4 f0 = ((const float4*)ap)[0];
      float4 f1 = ((const float4*)ap)[1];
      float4 f2 = ((const float4*)ap)[2];
      float4 f3 = ((const float4*)ap)[3];
      ushort8 u0, u1;
      u0[0] = f2bf(f0.x); u0[1] = f2bf(f0.y); u0[2] = f2bf(f0.z); u0[3] = f2bf(f0.w);
      u0[4] = f2bf(f1.x); u0[5] = f2bf(f1.y); u0[6] = f2bf(f1.z); u0[7] = f2bf(f1.w);
      u1[0] = f2bf(f2.x); u1[1] = f2bf(f2.y); u1[2] = f2bf(f2.z); u1[3] = f2bf(f2.w);
      u1[4] = f2bf(f3.x); u1[5] = f2bf(f3.y); u1[6] = f2bf(f3.z); u1[7] = f2bf(f3.w);
      ushort8* dst = (ushort8*)(Ad + row * 32 + cs);
      dst[0] = u0;
      dst[1] = u1;
    } else {
#pragma unroll
      for (int is = 0; is < TM / 64; is++) {
        int rbase = wave * (TM / 4) + is * 16;
        const unsigned short* g = Ab16 + (long)(rbase + srow) * lda + k0 + scol;
        __builtin_amdgcn_global_load_lds(
            (const __attribute__((address_space(1))) unsigned int*)g,
            (__attribute__((address_space(3))) unsigned int*)(Ad + rbase * 32), 16, 0, 0);
      }
    }
#pragma unroll
    for (int is = 0; is < 2; is++) {
      int rbase = wave * 32 + is * 16;
      const unsigned short* g = Bb + (long)(rbase + srow) * ldb + k0 + scol;
      __builtin_amdgcn_global_load_lds(
          (const __attribute__((address_space(1))) unsigned int*)g,
          (__attribute__((address_space(3))) unsigned int*)(Bd + rbase * 32), 16, 0, 0);
    }
  };

  stage(0, 0);
  int cur = 0;
  for (int k0 = 0; k0 < K; k0 += 32, cur ^= 1) {
    __syncthreads();  // drains vmcnt: As/Bs[cur] ready; prev reads of [cur] done
    if (k0 + 32 < K) stage(cur ^ 1, k0 + 32);

    const unsigned short* Ar = As + cur * (TM * 32);
    const unsigned short* Br = Bs + cur * (128 * 32);
    bf16x8 af[MI], bfv[4];
#pragma unroll
    for (int i = 0; i < MI; i++)
      af[i] = *(const bf16x8*)(Ar + (wm + i * 16 + fr) * 32 + ko);
#pragma unroll
    for (int j = 0; j < 4; j++)
      bfv[j] = *(const bf16x8*)(Br + (wn + j * 16 + fr) * 32 + ko);
#pragma unroll
    for (int i = 0; i < MI; i++)
#pragma unroll
      for (int j = 0; j < 4; j++)
        acc[i][j] = __builtin_amdgcn_mfma_f32_16x16x32_bf16(af[i], bfv[j], acc[i][j], 0, 0, 0);
  }

  // epilogue: C/D layout col=lane&15, row=(lane>>4)*4+r
  long cfo = c_off + zh * c_hi + zl * c_lo;
  long cbo = cb_off + zh * cb_hi + zl * cb_lo;
  int rq = (lane >> 4) * 4;
#pragma unroll
  for (int i = 0; i < MI; i++) {
    long rbase = m0 + wm + i * 16 + rq;
#pragma unroll
    for (int j = 0; j < 4; j++) {
      long cc = n0 + wn + j * 16 + fr;
      float bsv = BIAS ? bias[cc] : 0.f;
      long p = KVSPLIT ? ((cc >> 10) * cb_hi + (cc & 1023)) : cc;
#pragma unroll
      for (int r = 0; r < 4; r++) {
        float v = acc[i][j][r] + bsv;
        long ro = rbase + r;
        if constexpr (RES) v += Res[cfo + ro * ldc + cc];
        if constexpr (ACT == 1) v = 0.5f * v * (1.f + erff(v * 0.7071067811865475f));
        if constexpr (ACT == 2) v = 1.f / (1.f + __expf(-v));
        if constexpr (OUTF) Cf[cfo + ro * ldc + cc] = v;
        if constexpr (OUTB) Cb[cbo + ro * ldcb + p] = f2bf(v);
      }
    }
  }
}

// ---------------------------------------------------------------------------
// 256x256-tile deep-pipelined NT GEMM, specialized for the KV projection:
//   A bf16 [32768][1024], B bf16 [2048][1024] (wk||wv), C bf16 planar KV split.
// 8 waves (2M x 4N), BK=32, 4 K-tile LDS buffers (4 x 32 KiB = 128 KiB).
// Per K-tile: 2 phases x {ds_read frags | 2 global_load_lds prefetch (t+3) |
//   s_barrier | lgkmcnt(0) | setprio(1) 16xMFMA setprio(0) | s_barrier};
// counted s_waitcnt vmcnt(8) only at K-tile boundaries (never vmcnt(0)).
// LDS st-swizzle: within each 1KiB (16row x 32col) subtile, byte bit5 ^= bit9
// (i.e. 16B-slot bit1 ^= row bit3). Applied on BOTH sides: ds_read address is
// swizzled; global_load_lds dest stays linear and the per-lane GLOBAL source
// column is inverse-swizzled (same involution) -> rule #21 satisfied.
//
// Sync ledger (race audit):
//  - buffer b holds tile t (b = t&3); its loads are issued during tile t-3's
//    phases. vmcnt(8) before the trailing barrier of tile t-1 retires them
//    (in-order retire: <=8 outstanding = tiles t+1,t+2 only); the barrier then
//    publishes to all waves before any tile-t ds_read.
//  - writes for tile t+4 into buffer b are issued during tile t+1's phases,
//    i.e. after the tile-t trailing barrier, by which point every wave's
//    tile-t ds_reads of b completed (own lgkmcnt(0) before its MFMA).
// ---------------------------------------------------------------------------
__global__ __launch_bounds__(512, 2) void gemm256_kv_kernel(
    const unsigned short* __restrict__ A,   // [32768][1024] bf16
    const unsigned short* __restrict__ B,   // [2048][1024] bf16 (wk||wv)
    const float* __restrict__ bias,         // [2048] (bk||bv)
    unsigned short* __restrict__ C,         // K plane; V plane at +plane elems
    long plane) {
  __shared__ __align__(1024) unsigned short lds[4][2][8192];  // [buf][A/B][256*32]
  const int K = 1024, NT = 32;
  int tid = threadIdx.x;
  int wave = tid >> 6, lane = tid & 63;
  int wr = wave >> 2, wc = wave & 3;
  int fr = lane & 15, hi = lane >> 4;

  // XCD-bijective swizzle (1024 wgs, 8 XCDs): each XCD owns one 256-col B panel.
  int wg = ((blockIdx.x & 7) << 7) | (blockIdx.x >> 3);
  long m0 = (long)(wg & 127) * 256;
  int n0 = (wg >> 7) * 256;

  const unsigned short* Ab = A + m0 * K;
  const unsigned short* Bb = B + (long)n0 * K;

  // staging: per wave per tile, 4 x global_load_lds of 1KiB segments.
  // lane -> seg-local dest byte lane*16; source col inverse-swizzled.
  int lr = lane >> 2;
  int lc = (((lane & 3) ^ ((lane >> 5) << 1)) << 3);  // element col in [0,32)

  auto stageA = [&](int buf, int k0) {
    const unsigned short* g0 = Ab + (long)(wave * 16 + lr) * K + k0 + lc;
    __builtin_amdgcn_global_load_lds(
        (const __attribute__((address_space(1))) unsigned int*)g0,
        (__attribute__((address_space(3))) unsigned int*)&lds[buf][0][wave * 512], 16, 0, 0);
    const unsigned short* g1 = g0 + (long)128 * K;
    __builtin_amdgcn_global_load_lds(
        (const __attribute__((address_space(1))) unsigned int*)g1,
        (__attribute__((address_space(3))) unsigned int*)&lds[buf][0][4096 + wave * 512], 16, 0, 0);
  };
  auto stageB = [&](int buf, int k0) {
    const unsigned short* g0 = Bb + (long)(wave * 16 + lr) * K + k0 + lc;
    __builtin_amdgcn_global_load_lds(
        (const __attribute__((address_space(1))) unsigned int*)g0,
        (__attribute__((address_space(3))) unsigned int*)&lds[buf][1][wave * 512], 16, 0, 0);
    const unsigned short* g1 = g0 + (long)128 * K;
    __builtin_amdgcn_global_load_lds(
        (const __attribute__((address_space(1))) unsigned int*)g1,
        (__attribute__((address_space(3))) unsigned int*)&lds[buf][1][4096 + wave * 512], 16, 0, 0);
  };

  // read-side swizzled column (element units): hi*8 with 16B-slot bit1 ^= fr bit3
  int cbel = ((hi * 16) ^ ((fr >> 3) << 5)) >> 1;
  int aoff = (wr * 128 + fr) * 32 + cbel;
  int boff = (wc * 64 + fr) * 32 + cbel;

  f32x4 acc[8][4] = {};

  // prologue: stage tiles 0,1,2 (12 loads/wave), retire through tile 0.
#pragma unroll
  for (int t = 0; t < 3; t++) { stageA(t, t * 32); stageB(t, t * 32); }
  asm volatile("s_waitcnt vmcnt(8)" ::: "memory");
  __builtin_amdgcn_s_barrier();

#pragma unroll 4
  for (int t = 0; t < NT; t++) {
    int buf = t & 3;
    const unsigned short* Abuf = &lds[buf][0][0];
    const unsigned short* Bbuf = &lds[buf][1][0];
    bf16x8 af[4], bfv[4];

    // ---- phase 1: m-half 0 ----
#pragma unroll
    for (int i = 0; i < 4; i++)
      af[i] = *(const bf16x8*)(Abuf + aoff + i * 512);
#pragma unroll
    for (int n = 0; n < 4; n++)
      bfv[n] = *(const bf16x8*)(Bbuf + boff + n * 512);
    if (t + 3 < NT) stageA((t + 3) & 3, (t + 3) * 32);
    __builtin_amdgcn_s_barrier();
    asm volatile("s_waitcnt lgkmcnt(0)" ::: "memory");
    __builtin_amdgcn_sched_barrier(0);
    __builtin_amdgcn_s_setprio(1);
#pragma unroll
    for (int i = 0; i < 4; i++)
#pragma unroll
      for (int n = 0; n < 4; n++)
        acc[i][n] = __builtin_amdgcn_mfma_f32_16x16x32_bf16(af[i], bfv[n], acc[i][n], 0, 0, 0);
    __builtin_amdgcn_s_setprio(0);
    __builtin_amdgcn_s_barrier();

    // ---- phase 2: m-half 1 ----
#pragma unroll
    for (int i = 0; i < 4; i++)
      af[i] = *(const bf16x8*)(Abuf + aoff + 2048 + i * 512);
    if (t + 3 < NT) stageB((t + 3) & 3, (t + 3) * 32);
    __builtin_amdgcn_s_barrier();
    asm volatile("s_waitcnt lgkmcnt(0)" ::: "memory");
    __builtin_amdgcn_sched_barrier(0);
    __builtin_amdgcn_s_setprio(1);
#pragma unroll
    for (int i = 0; i < 4; i++)
#pragma unroll
      for (int n = 0; n < 4; n++)
        acc[4 + i][n] = __builtin_amdgcn_mfma_f32_16x16x32_bf16(af[i], bfv[n], acc[4 + i][n], 0, 0, 0);
    __builtin_amdgcn_s_setprio(0);
    asm volatile("s_waitcnt vmcnt(8)" ::: "memory");  // tile t+1 fully resident
    __builtin_amdgcn_s_barrier();
  }

  // epilogue: C/D layout col=lane&15, row=(lane>>4)*4+r; planar KV split
  int rq = hi * 4;
#pragma unroll
  for (int i = 0; i < 8; i++) {
    long r0 = m0 + wr * 128 + i * 16 + rq;
#pragma unroll
    for (int n = 0; n < 4; n++) {
      int cc = n0 + wc * 64 + n * 16 + fr;
      float bsv = bias[cc];
      long p = (long)(cc >> 10) * plane + (cc & 1023);
#pragma unroll
      for (int r = 0; r < 4; r++)
        C[p + (r0 + r) * 1024] = f2bf(acc[i][n][r] + bsv);
    }
  }
}

// ---------------------------------------------------------------------------
// Host side
// ---------------------------------------------------------------------------
template <int TM, bool AF32, bool BIAS, int ACT, bool RES, bool OUTF, bool OUTB, bool KVSPLIT = false>
static void launch_gemm(hipStream_t s, int M, int N, int K, int nz, int zdiv,
                        const void* A, long a_off, int lda, long a_hi, long a_lo,
                        const unsigned short* B, long b_off, int ldb, long b_hi, long b_lo,
                        const float* bias, const float* Res,
                        float* Cf, long c_off, int ldc, long c_hi, long c_lo,
                        unsigned short* Cb, long cb_off, int ldcb, long cb_hi, long cb_lo) {
  dim3 g(M / TM, N / 128, nz);
  gemm_nt_kernel<TM, AF32, BIAS, ACT, RES, OUTF, OUTB, KVSPLIT><<<g, dim3(256), 0, s>>>(
      A, a_off, lda, a_hi, a_lo, B, b_off, ldb, b_hi, b_lo, bias, Res,
      Cf, c_off, ldc, c_hi, c_lo, Cb, cb_off, ldcb, cb_hi, cb_lo, K, zdiv);
}

// workspace layout (bytes). Weight regions 0..40MiB are CONTIGUOUS in cast order.
static const long WB_SAIN = 0;          // 6 MiB
static const long WB_SAOUT = 6291456;   // 2 MiB
static const long WB_WQ = 8388608;      // 2 MiB
static const long WB_WK = 10485760;     // 2 MiB  (wk||wv contiguous -> fused KV B)
static const long WB_WV = 12582912;     // 2 MiB
static const long WB_WO = 14680064;     // 2 MiB
static const long WB_W1 = 16777216;     // 8 MiB
static const long WB_W2 = 25165824;     // 8 MiB
static const long WB_MW = 33554432;     // 8 MiB
static const long OF_K = 41943040;      // 64 MiB: K planar; later V^T
static const long OF_V = 109051904;     // 64 MiB: V planar
static const long OF_QKV = 176160768;   // 12 MiB: qkv bf16; later x1 (fp32, 8 MiB)
static const long OF_BKV = 187695104;   // 8 KiB: concat [bk;bv]
static const long OF_SC = 188743680;    // 32 MiB: self-sc / cross-sc / x2 (fp32)
static const long OF_P = 222298112;     // 16 MiB: attn_p / attn2 / h (bf16)
static const long OF_QN = 239075328;    // 4 MiB: LN outs / self V^T (time-disjoint)
static const long OF_Q = 243269632;     // 4 MiB: Q proj
static const long OF_CTX = 247463936;   // 4 MiB: ctx / ctx2 / x3_bf  (end 251658240)
static const long OF_MEMBF = 251658240; // 64 MiB: memory cast to bf16 (fast path only)
static const size_t FAST_WS = 318767104;

extern "C" void kernel_launch(void* const* d_in, const int* in_sizes, int n_in,
                              void* d_out, int out_size, void* d_ws, size_t ws_size,
                              hipStream_t stream) {
  (void)in_sizes; (void)n_in; (void)out_size;
  const float* query = (const float*)d_in[0];
  const float* memoryp = (const float*)d_in[1];
  const float* prev_mask = (const float*)d_in[2];
  const float* sa_in_w = (const float*)d_in[5];
  const float* sa_in_b = (const float*)d_in[6];
  const float* sa_out_w = (const float*)d_in[7];
  const float* sa_out_b = (const float*)d_in[8];
  const float* ln1_g = (const float*)d_in[9], * ln1_b = (const float*)d_in[10];
  const float* ln2_g = (const float*)d_in[11], * ln2_b = (const float*)d_in[12];
  const float* ln3_g = (const float*)d_in[13], * ln3_b = (const float*)d_in[14];
  const float* wq = (const float*)d_in[15], * bq = (const float*)d_in[16];
  const float* wk = (const float*)d_in[17], * bk = (const float*)d_in[18];
  const float* wv = (const float*)d_in[19], * bv = (const float*)d_in[20];
  const float* wo = (const float*)d_in[21], * bo = (const float*)d_in[22];
  const float* w1 = (const float*)d_in[23], * b1 = (const float*)d_in[24];
  const float* w2 = (const float*)d_in[25], * b2 = (const float*)d_in[26];
  const float* mask_w = (const float*)d_in[27], * mask_b = (const float*)d_in[28];

  uint8_t* ws = (uint8_t*)d_ws;
  auto bf = [&](long off) { return (unsigned short*)(ws + off); };
  auto fp = [&](long off) { return (float*)(ws + off); };
  unsigned short* ZB = nullptr;
  float* ZF = nullptr;
  const bool fast = ws_size >= FAST_WS;

  // ---- all 9 weight casts in one launch (dst = ws[0..40MiB) contiguous) ----
  {
    CastSegs cs;
    const float* srcs[9] = {sa_in_w, sa_out_w, wq, wk, wv, wo, w1, w2, mask_w};
    int n8s[9] = {393216, 131072, 131072, 131072, 131072, 131072, 524288, 524288, 524288};
    int c = 0;
    for (int i = 0; i < 9; i++) { cs.src[i] = srcs[i]; cs.cum[i] = c; c += n8s[i]; }
    cs.cum[9] = c;  // 2621440
    cast_multi_kernel<<<dim3((c + 255) / 256), dim3(256), 0, stream>>>(cs, bf(0));
  }

  // ---- self attention ----
  ln_bf16_kernel<<<2048, 256, 0, stream>>>(query, ln1_g, ln1_b, bf(OF_QN));

  // qkv = qn @ sa_in_w^T + b  -> bf16 [2048 x 3072]
  launch_gemm<128, false, true, 0, false, false, true>(stream, 2048, 3072, 1024, 1, 1,
      bf(OF_QN), 0, 1024, 0, 0, bf(WB_SAIN), 0, 1024, 0, 0, sa_in_b, nullptr,
      ZF, 0, 0, 0, 0, bf(OF_QKV), 0, 3072, 0, 0);

  // self scores [b,h][256][256] fp32; z=(b*8+h)
  launch_gemm<128, false, false, 0, false, true, false>(stream, 256, 256, 128, 64, 8,
      bf(OF_QKV), 0, 24576, 3072, 128,
      bf(OF_QKV), 1024, 24576, 3072, 128, nullptr, nullptr,
      fp(OF_SC), 0, 256, 524288, 65536, ZB, 0, 0, 0, 0);

  softmax_bf16_kernel<false, 1><<<16384, 256, 0, stream>>>(
      fp(OF_SC), nullptr, bf(OF_P), 0.08838834764831845f);

  // self V^T: VT_s[z=(b*8+h)][d=128][s=256]
  transpose_bf16_kernel<<<dim3(4, 8, 64), 256, 0, stream>>>(
      bf(OF_QKV), bf(OF_QN), 2048L, 24576, 3072L, 128L, 8, 0L, 256, 262144L, 32768L);

  // ctx = attn_p @ VT_s^T  (TM=64 -> 256 blocks)
  launch_gemm<64, false, false, 0, false, false, true>(stream, 256, 128, 256, 64, 8,
      bf(OF_P), 0, 256, 524288, 65536,
      bf(OF_QN), 0, 256, 262144, 32768, nullptr, nullptr,
      ZF, 0, 0, 0, 0, bf(OF_CTX), 0, 8192, 1024, 128);

  // x1 = query + ctx @ sa_out_w^T + b -> fp32 at OF_QKV (TM=64)
  launch_gemm<64, false, true, 0, true, true, false>(stream, 2048, 1024, 1024, 1, 1,
      bf(OF_CTX), 0, 1024, 0, 0, bf(WB_SAOUT), 0, 1024, 0, 0, sa_out_b, query,
      fp(OF_QKV), 0, 1024, 0, 0, ZB, 0, 0, 0, 0);

  // ---- cross attention ----
  ln_bf16_kernel<<<2048, 256, 0, stream>>>(fp(OF_QKV), ln2_g, ln2_b, bf(OF_QN));

  launch_gemm<64, false, true, 0, false, false, true>(stream, 2048, 1024, 1024, 1, 1,
      bf(OF_QN), 0, 1024, 0, 0, bf(WB_WQ), 0, 1024, 0, 0, bq, nullptr,
      ZF, 0, 0, 0, 0, bf(OF_Q), 0, 1024, 0, 0);

  // fused K,V projection: [32768 x 2048] vs wk||wv, planar outputs K@OF_K, V@OF_V
  bias_concat_kernel<<<8, 256, 0, stream>>>(bk, bv, fp(OF_BKV));
  if (fast) {
    cast_bf16_kernel<<<16384, 256, 0, stream>>>(memoryp, bf(OF_MEMBF), 4194304);
    gemm256_kv_kernel<<<dim3(1024), dim3(512), 0, stream>>>(
        bf(OF_MEMBF), bf(WB_WK), fp(OF_BKV), bf(OF_K), 33554432L);
  } else {
    launch_gemm<128, true, true, 0, false, false, true, true>(stream, 32768, 2048, 1024, 1, 1,
        memoryp, 0, 1024, 0, 0, bf(WB_WK), 0, 1024, 0, 0, fp(OF_BKV), nullptr,
        ZF, 0, 0, 0, 0, bf(OF_K), 0, 1024, 33554432, 0);
  }

  // cross scores [b][256][4096] fp32
  launch_gemm<128, false, false, 0, false, true, false>(stream, 256, 4096, 1024, 8, 1,
      bf(OF_Q), 0, 8192, 1024, 0,
      bf(OF_K), 0, 8192, 1024, 0, nullptr, nullptr,
      fp(OF_SC), 0, 4096, 1048576, 0, ZB, 0, 0, 0, 0);

  softmax_bf16_kernel<true, 16><<<2048, 256, 0, stream>>>(
      fp(OF_SC), prev_mask, bf(OF_P), 0.03125f);

  // V^T[b][d=1024][s=4096] into OF_K region (K dead now)
  transpose_bf16_kernel<<<dim3(32, 128, 8), 256, 0, stream>>>(
      bf(OF_V), bf(OF_K), 0L, 8192, 1024L, 0L, 1, 0L, 4096, 4194304L, 0L);

  // ctx2 = attn2 @ VT^T (TM=64 -> 256 blocks)
  launch_gemm<64, false, false, 0, false, false, true>(stream, 256, 1024, 4096, 8, 1,
      bf(OF_P), 0, 4096, 1048576, 0,
      bf(OF_K), 0, 4096, 4194304, 0, nullptr, nullptr,
      ZF, 0, 0, 0, 0, bf(OF_CTX), 0, 8192, 1024, 0);

  // x2 = x1 + ctx2 @ wo^T + bo -> fp32 at OF_SC (TM=64)
  launch_gemm<64, false, true, 0, true, true, false>(stream, 2048, 1024, 1024, 1, 1,
      bf(OF_CTX), 0, 1024, 0, 0, bf(WB_WO), 0, 1024, 0, 0, bo, fp(OF_QKV),
      fp(OF_SC), 0, 1024, 0, 0, ZB, 0, 0, 0, 0);

  // ---- FFN ----
  ln_bf16_kernel<<<2048, 256, 0, stream>>>(fp(OF_SC), ln3_g, ln3_b, bf(OF_QN));

  // h = gelu(qn3 @ w1^T + b1) -> bf16 [2048 x 4096]
  launch_gemm<128, false, true, 1, false, false, true>(stream, 2048, 4096, 1024, 1, 1,
      bf(OF_QN), 0, 1024, 0, 0, bf(WB_W1), 0, 1024, 0, 0, b1, nullptr,
      ZF, 0, 0, 0, 0, bf(OF_P), 0, 4096, 0, 0);

  // x3 = x2 + h @ w2^T + b2 -> d_out (fp32) and bf16 copy (TM=64)
  launch_gemm<64, false, true, 0, true, true, true>(stream, 2048, 1024, 4096, 1, 1,
      bf(OF_P), 0, 4096, 0, 0, bf(WB_W2), 0, 4096, 0, 0, b2, fp(OF_SC),
      (float*)d_out, 0, 1024, 0, 0, bf(OF_CTX), 0, 1024, 0, 0);

  // pred_mask[b][q][4096] = sigmoid(x3 @ mask_w^T + mask_b)
  launch_gemm<128, false, true, 2, false, true, false>(stream, 256, 4096, 1024, 8, 1,
      bf(OF_CTX), 0, 8192, 1024, 0,
      bf(WB_MW), 0, 1024, 0, 0, mask_b, nullptr,
      (float*)d_out + 2097152, 0, 4096, 1048576, 0, ZB, 0, 0, 0, 0);
}

// Round 2
// 949.221 us; speedup vs baseline: 1.0582x; 1.0029x over previous
//
#include <hip/hip_runtime.h>
#include <cstdint>

// ---------------------------------------------------------------------------
// MaskedTransformerDecoderLayer on MI355X.
// All GEMMs: bf16-MFMA tiles (16x16x32), fp32 accumulate, double-buffered LDS.
// D=1024, NHEAD=8, NQ=256, B=8, S=4096, FF=4096.
// This round: KV-projection 256^2 kernel gets an L2-locality block remap
// (XCD owns an m-chunk, n swept fastest) replacing the n-panel-per-XCD
// swizzle that forced every XCD to stream the full 64 MiB A matrix.
// ---------------------------------------------------------------------------

typedef __attribute__((ext_vector_type(8))) __bf16 bf16x8;
typedef __attribute__((ext_vector_type(4))) float f32x4;
typedef __attribute__((ext_vector_type(8))) unsigned short ushort8;
typedef __attribute__((ext_vector_type(4))) unsigned short ushort4v;

__device__ __forceinline__ unsigned short f2bf(float f) {
  return __builtin_bit_cast(unsigned short, (__bf16)f);
}

// ---------------- cast fp32 -> bf16 (8 elems/thread) ----------------
__global__ __launch_bounds__(256) void cast_bf16_kernel(const float* __restrict__ in,
                                                        unsigned short* __restrict__ out,
                                                        int n8) {
  int i = blockIdx.x * 256 + threadIdx.x;
  if (i >= n8) return;
  const float4* p = (const float4*)in + (size_t)i * 2;
  float4 a = p[0], b = p[1];
  ushort8 o;
  o[0] = f2bf(a.x); o[1] = f2bf(a.y); o[2] = f2bf(a.z); o[3] = f2bf(a.w);
  o[4] = f2bf(b.x); o[5] = f2bf(b.y); o[6] = f2bf(b.z); o[7] = f2bf(b.w);
  ((ushort8*)out)[i] = o;
}

// ---------------- fused multi-tensor cast (dst regions contiguous) ----------
struct CastSegs {
  const float* src[9];
  int cum[10];  // cumulative n8 counts
};
__global__ __launch_bounds__(256) void cast_multi_kernel(CastSegs cs,
                                                         unsigned short* __restrict__ out) {
  int i = blockIdx.x * 256 + threadIdx.x;
  if (i >= cs.cum[9]) return;
  int s = 0;
  while (i >= cs.cum[s + 1]) s++;
  const float4* p = (const float4*)cs.src[s] + (size_t)(i - cs.cum[s]) * 2;
  float4 a = p[0], b = p[1];
  ushort8 o;
  o[0] = f2bf(a.x); o[1] = f2bf(a.y); o[2] = f2bf(a.z); o[3] = f2bf(a.w);
  o[4] = f2bf(b.x); o[5] = f2bf(b.y); o[6] = f2bf(b.z); o[7] = f2bf(b.w);
  ((ushort8*)out)[i] = o;
}

__global__ __launch_bounds__(256) void bias_concat_kernel(const float* __restrict__ a,
                                                          const float* __restrict__ b,
                                                          float* __restrict__ o) {
  int i = blockIdx.x * 256 + threadIdx.x;
  o[i] = i < 1024 ? a[i] : b[i - 1024];
}

// ---------------- LayerNorm over D=1024, bf16 out ----------------
__global__ __launch_bounds__(256) void ln_bf16_kernel(const float* __restrict__ x,
                                                      const float* __restrict__ g,
                                                      const float* __restrict__ b,
                                                      unsigned short* __restrict__ out) {
  int row = blockIdx.x, tid = threadIdx.x;
  const float4* xr = (const float4*)(x + (size_t)row * 1024);
  float4 v = xr[tid];
  float s = v.x + v.y + v.z + v.w;
  float sq = v.x * v.x + v.y * v.y + v.z * v.z + v.w * v.w;
#pragma unroll
  for (int o = 32; o > 0; o >>= 1) { s += __shfl_xor(s, o); sq += __shfl_xor(sq, o); }
  __shared__ float red[8];
  int wave = tid >> 6, lane = tid & 63;
  if (lane == 0) { red[wave] = s; red[4 + wave] = sq; }
  __syncthreads();
  float ts = red[0] + red[1] + red[2] + red[3];
  float tq = red[4] + red[5] + red[6] + red[7];
  float mean = ts * (1.f / 1024.f);
  float var = tq * (1.f / 1024.f) - mean * mean;
  float rstd = rsqrtf(var + 1e-5f);
  float4 gv = ((const float4*)g)[tid];
  float4 bv = ((const float4*)b)[tid];
  ushort4v o;
  o[0] = f2bf((v.x - mean) * rstd * gv.x + bv.x);
  o[1] = f2bf((v.y - mean) * rstd * gv.y + bv.y);
  o[2] = f2bf((v.z - mean) * rstd * gv.z + bv.z);
  o[3] = f2bf((v.w - mean) * rstd * gv.w + bv.w);
  ((ushort4v*)(out + (size_t)row * 1024))[tid] = o;
}

// ---------------- rowwise softmax, optional +log(mask+1e-6), bf16 out -------
template <bool MASK, int CNT>
__global__ __launch_bounds__(256) void softmax_bf16_kernel(const float* __restrict__ sc,
                                                           const float* __restrict__ pm,
                                                           unsigned short* __restrict__ out,
                                                           float scale) {
  const int L = CNT * 256;
  int row = blockIdx.x, tid = threadIdx.x;
  const float* sr = sc + (size_t)row * L;
  float vals[CNT];
  float mx = -1e30f;
#pragma unroll
  for (int i = 0; i < CNT; i++) {
    int idx = tid + (i << 8);
    float v = sr[idx] * scale;
    if (MASK) v += __logf(pm[(size_t)row * L + idx] + 1e-6f);
    vals[i] = v;
    mx = fmaxf(mx, v);
  }
#pragma unroll
  for (int o = 32; o > 0; o >>= 1) mx = fmaxf(mx, __shfl_xor(mx, o));
  __shared__ float red[8];
  int wave = tid >> 6, lane = tid & 63;
  if (lane == 0) red[wave] = mx;
  __syncthreads();
  mx = fmaxf(fmaxf(red[0], red[1]), fmaxf(red[2], red[3]));
  float sum = 0.f;
#pragma unroll
  for (int i = 0; i < CNT; i++) { vals[i] = __expf(vals[i] - mx); sum += vals[i]; }
#pragma unroll
  for (int o = 32; o > 0; o >>= 1) sum += __shfl_xor(sum, o);
  if (lane == 0) red[4 + wave] = sum;
  __syncthreads();
  float rs = 1.f / (red[4] + red[5] + red[6] + red[7]);
#pragma unroll
  for (int i = 0; i < CNT; i++)
    out[(size_t)row * L + tid + (i << 8)] = f2bf(vals[i] * rs);
}

// ---------------- batched bf16 transpose (32x32 tiles via LDS) ----------------
__global__ __launch_bounds__(256) void transpose_bf16_kernel(
    const unsigned short* __restrict__ in, unsigned short* __restrict__ out,
    long in_off, int in_rs, long in_hi, long in_lo, int zdiv,
    long out_off, int out_rs, long out_hi, long out_lo) {
  __shared__ unsigned short t[32][33];
  int z = blockIdx.z;
  int zh = z / zdiv, zl = z % zdiv;
  const unsigned short* ib = in + in_off + (long)zh * in_hi + (long)zl * in_lo;
  unsigned short* ob = out + out_off + (long)zh * out_hi + (long)zl * out_lo;
  int i0 = blockIdx.x * 32;
  int j0 = blockIdx.y * 32;
  int tx = threadIdx.x & 31, ty = threadIdx.x >> 5;
#pragma unroll
  for (int r = ty; r < 32; r += 8) t[r][tx] = ib[(long)(j0 + r) * in_rs + i0 + tx];
  __syncthreads();
#pragma unroll
  for (int r = ty; r < 32; r += 8) ob[(long)(i0 + r) * out_rs + j0 + tx] = t[tx][r];
}

// ---------------- batched NT GEMM: C[m,n] = sum_k A[m,k]*B[n,k] ----------------
// Tile TM x 128, BK=32, 4 waves (2x2), DOUBLE-BUFFERED LDS.
template <int TM, bool AF32, bool BIAS, int ACT, bool RES, bool OUTF, bool OUTB, bool KVSPLIT>
__global__ __launch_bounds__(256) void gemm_nt_kernel(
    const void* __restrict__ Av, long a_off, int lda, long a_hi, long a_lo,
    const unsigned short* __restrict__ B, long b_off, int ldb, long b_hi, long b_lo,
    const float* __restrict__ bias, const float* __restrict__ Res,
    float* __restrict__ Cf, long c_off, int ldc, long c_hi, long c_lo,
    unsigned short* __restrict__ Cb, long cb_off, int ldcb, long cb_hi, long cb_lo,
    int K, int zdiv) {
  constexpr int MI = TM / 32;
  __shared__ unsigned short As[2 * TM * 32];
  __shared__ unsigned short Bs[2 * 128 * 32];
  int tid = threadIdx.x;
  int wave = tid >> 6, lane = tid & 63;
  int z = blockIdx.z, zh = z / zdiv, zl = z % zdiv;
  long m0 = (long)blockIdx.x * TM, n0 = (long)blockIdx.y * 128;

  const unsigned short* Bb = B + b_off + zh * b_hi + zl * b_lo + n0 * ldb;
  const unsigned short* Ab16 = nullptr;
  const float* Abf = nullptr;
  if constexpr (AF32)
    Abf = (const float*)Av + a_off + zh * a_hi + zl * a_lo + m0 * lda;
  else
    Ab16 = (const unsigned short*)Av + a_off + zh * a_hi + zl * a_lo + m0 * lda;

  int srow = lane >> 2;
  int scol = (lane & 3) * 8;
  int wm = (wave >> 1) * (TM / 2), wn = (wave & 1) * 64;
  int fr = lane & 15;
  int ko = (lane >> 4) * 8;

  f32x4 acc[MI][4] = {};

  auto stage = [&](int buf, int k0) {
    unsigned short* Ad = As + buf * (TM * 32);
    unsigned short* Bd = Bs + buf * (128 * 32);
    if constexpr (AF32) {
      int row = tid >> 1;
      int cs = (tid & 1) * 16;
      const float* ap = Abf + (long)row * lda + k0 + cs;
      float4 f0 = ((const float4*)ap)[0];
      float4 f1 = ((const float4*)ap)[1];
      float4 f2 = ((const float4*)ap)[2];
      float4 f3 = ((const float4*)ap)[3];
      ushort8 u0, u1;
      u0[0] = f2bf(f0.x); u0[1] = f2bf(f0.y); u0[2] = f2bf(f0.z); u0[3] = f2bf(f0.w);
      u0[4] = f2bf(f1.x); u0[5] = f2bf(f1.y); u0[6] = f2bf(f1.z); u0[7] = f2bf(f1.w);
      u1[0] = f2bf(f2.x); u1[1] = f2bf(f2.y); u1[2] = f2bf(f2.z); u1[3] = f2bf(f2.w);
      u1[4] = f2bf(f3.x); u1[5] = f2bf(f3.y); u1[6] = f2bf(f3.z); u1[7] = f2bf(f3.w);
      ushort8* dst = (ushort8*)(Ad + row * 32 + cs);
      dst[0] = u0;
      dst[1] = u1;
    } else {
#pragma unroll
      for (int is = 0; is < TM / 64; is++) {
        int rbase = wave * (TM / 4) + is * 16;
        const unsigned short* g = Ab16 + (long)(rbase + srow) * lda + k0 + scol;
        __builtin_amdgcn_global_load_lds(
            (const __attribute__((address_space(1))) unsigned int*)g,
            (__attribute__((address_space(3))) unsigned int*)(Ad + rbase * 32), 16, 0, 0);
      }
    }
#pragma unroll
    for (int is = 0; is < 2; is++) {
      int rbase = wave * 32 + is * 16;
      const unsigned short* g = Bb + (long)(rbase + srow) * ldb + k0 + scol;
      __builtin_amdgcn_global_load_lds(
          (const __attribute__((address_space(1))) unsigned int*)g,
          (__attribute__((address_space(3))) unsigned int*)(Bd + rbase * 32), 16, 0, 0);
    }
  };

  stage(0, 0);
  int cur = 0;
  for (int k0 = 0; k0 < K; k0 += 32, cur ^= 1) {
    __syncthreads();  // drains vmcnt: As/Bs[cur] ready; prev reads of [cur] done
    if (k0 + 32 < K) stage(cur ^ 1, k0 + 32);

    const unsigned short* Ar = As + cur * (TM * 32);
    const unsigned short* Br = Bs + cur * (128 * 32);
    bf16x8 af[MI], bfv[4];
#pragma unroll
    for (int i = 0; i < MI; i++)
      af[i] = *(const bf16x8*)(Ar + (wm + i * 16 + fr) * 32 + ko);
#pragma unroll
    for (int j = 0; j < 4; j++)
      bfv[j] = *(const bf16x8*)(Br + (wn + j * 16 + fr) * 32 + ko);
#pragma unroll
    for (int i = 0; i < MI; i++)
#pragma unroll
      for (int j = 0; j < 4; j++)
        acc[i][j] = __builtin_amdgcn_mfma_f32_16x16x32_bf16(af[i], bfv[j], acc[i][j], 0, 0, 0);
  }

  // epilogue: C/D layout col=lane&15, row=(lane>>4)*4+r
  long cfo = c_off + zh * c_hi + zl * c_lo;
  long cbo = cb_off + zh * cb_hi + zl * cb_lo;
  int rq = (lane >> 4) * 4;
#pragma unroll
  for (int i = 0; i < MI; i++) {
    long rbase = m0 + wm + i * 16 + rq;
#pragma unroll
    for (int j = 0; j < 4; j++) {
      long cc = n0 + wn + j * 16 + fr;
      float bsv = BIAS ? bias[cc] : 0.f;
      long p = KVSPLIT ? ((cc >> 10) * cb_hi + (cc & 1023)) : cc;
#pragma unroll
      for (int r = 0; r < 4; r++) {
        float v = acc[i][j][r] + bsv;
        long ro = rbase + r;
        if constexpr (RES) v += Res[cfo + ro * ldc + cc];
        if constexpr (ACT == 1) v = 0.5f * v * (1.f + erff(v * 0.7071067811865475f));
        if constexpr (ACT == 2) v = 1.f / (1.f + __expf(-v));
        if constexpr (OUTF) Cf[cfo + ro * ldc + cc] = v;
        if constexpr (OUTB) Cb[cbo + ro * ldcb + p] = f2bf(v);
      }
    }
  }
}

// ---------------------------------------------------------------------------
// 256x256-tile deep-pipelined NT GEMM, specialized for the KV projection:
//   A bf16 [32768][1024], B bf16 [2048][1024] (wk||wv), C bf16 planar KV split.
// 8 waves (2M x 4N), BK=32, 4 K-tile LDS buffers (4 x 32 KiB = 128 KiB).
// Per K-tile: 2 phases x {ds_read frags | 2 global_load_lds prefetch (t+3) |
//   s_barrier | lgkmcnt(0) | setprio(1) 16xMFMA setprio(0) | s_barrier};
// counted s_waitcnt vmcnt(8) only at K-tile boundaries (never vmcnt(0)).
// LDS st-swizzle: within each 1KiB (16row x 32col) subtile, byte bit5 ^= bit9.
// Applied BOTH sides (rule #21): linear global_load_lds dest + inverse-swz
// global source col + swz on ds_read address (same involution).
//
// Sync ledger (race audit — unchanged from R1, verified passing):
//  - buffer b holds tile t (b = t&3); its loads are issued during tile t-3's
//    phases. vmcnt(8) before the trailing barrier of tile t-1 retires them;
//    the barrier then publishes to all waves before any tile-t ds_read.
//  - writes for tile t+4 into buffer b are issued during tile t+1's phases,
//    i.e. after the tile-t trailing barrier, by which point every wave's
//    tile-t ds_reads of b completed (own lgkmcnt(0) before its MFMA).
//
// R2 change (index-only, no sync edits): L2-locality block remap.
//  Old: XCD owned one 256-col n-panel and swept all 128 m-tiles -> each XCD
//  streamed the full 64 MiB A through its 4 MiB L2 (FETCH_SIZE 270 MB,
//  ~11 TB/s L3 pressure, pipeline starved at MfmaUtil 37%).
//  New: XCD x = bid&7 owns m-tiles [16x,16x+16) x all 8 n-tiles; within an
//  XCD arrival order sweeps n fastest. Concurrent ~32 blocks/XCD touch
//  4 m-panels (2 MiB) + 8 n-panels (4 MiB) ~= L2-sized working set;
//  distinct A per XCD drops 64 MiB -> 8 MiB.
// ---------------------------------------------------------------------------
__global__ __launch_bounds__(512, 2) void gemm256_kv_kernel(
    const unsigned short* __restrict__ A,   // [32768][1024] bf16
    const unsigned short* __restrict__ B,   // [2048][1024] bf16 (wk||wv)
    const float* __restrict__ bias,         // [2048] (bk||bv)
    unsigned short* __restrict__ C,         // K plane; V plane at +plane elems
    long plane) {
  __shared__ __align__(1024) unsigned short lds[4][2][8192];  // [buf][A/B][256*32]
  const int K = 1024, NT = 32;
  int tid = threadIdx.x;
  int wave = tid >> 6, lane = tid & 63;
  int wr = wave >> 2, wc = wave & 3;
  int fr = lane & 15, hi = lane >> 4;

  // L2-locality remap (bijective: 1024 wgs, 1024%8==0).
  int l = blockIdx.x >> 3;
  long m0 = (long)((blockIdx.x & 7) * 16 + (l >> 3)) * 256;
  int n0 = (l & 7) * 256;

  const unsigned short* Ab = A + m0 * K;
  const unsigned short* Bb = B + (long)n0 * K;

  // staging: per wave per tile, 4 x global_load_lds of 1KiB segments.
  // lane -> seg-local dest byte lane*16; source col inverse-swizzled.
  int lr = lane >> 2;
  int lc = (((lane & 3) ^ ((lane >> 5) << 1)) << 3);  // element col in [0,32)

  auto stageA = [&](int buf, int k0) {
    const unsigned short* g0 = Ab + (long)(wave * 16 + lr) * K + k0 + lc;
    __builtin_amdgcn_global_load_lds(
        (const __attribute__((address_space(1))) unsigned int*)g0,
        (__attribute__((address_space(3))) unsigned int*)&lds[buf][0][wave * 512], 16, 0, 0);
    const unsigned short* g1 = g0 + (long)128 * K;
    __builtin_amdgcn_global_load_lds(
        (const __attribute__((address_space(1))) unsigned int*)g1,
        (__attribute__((address_space(3))) unsigned int*)&lds[buf][0][4096 + wave * 512], 16, 0, 0);
  };
  auto stageB = [&](int buf, int k0) {
    const unsigned short* g0 = Bb + (long)(wave * 16 + lr) * K + k0 + lc;
    __builtin_amdgcn_global_load_lds(
        (const __attribute__((address_space(1))) unsigned int*)g0,
        (__attribute__((address_space(3))) unsigned int*)&lds[buf][1][wave * 512], 16, 0, 0);
    const unsigned short* g1 = g0 + (long)128 * K;
    __builtin_amdgcn_global_load_lds(
        (const __attribute__((address_space(1))) unsigned int*)g1,
        (__attribute__((address_space(3))) unsigned int*)&lds[buf][1][4096 + wave * 512], 16, 0, 0);
  };

  // read-side swizzled column (element units): hi*8 with 16B-slot bit1 ^= fr bit3
  int cbel = ((hi * 16) ^ ((fr >> 3) << 5)) >> 1;
  int aoff = (wr * 128 + fr) * 32 + cbel;
  int boff = (wc * 64 + fr) * 32 + cbel;

  f32x4 acc[8][4] = {};

  // prologue: stage tiles 0,1,2 (12 loads/wave), retire through tile 0.
#pragma unroll
  for (int t = 0; t < 3; t++) { stageA(t, t * 32); stageB(t, t * 32); }
  asm volatile("s_waitcnt vmcnt(8)" ::: "memory");
  __builtin_amdgcn_s_barrier();

#pragma unroll 4
  for (int t = 0; t < NT; t++) {
    int buf = t & 3;
    const unsigned short* Abuf = &lds[buf][0][0];
    const unsigned short* Bbuf = &lds[buf][1][0];
    bf16x8 af[4], bfv[4];

    // ---- phase 1: m-half 0 ----
#pragma unroll
    for (int i = 0; i < 4; i++)
      af[i] = *(const bf16x8*)(Abuf + aoff + i * 512);
#pragma unroll
    for (int n = 0; n < 4; n++)
      bfv[n] = *(const bf16x8*)(Bbuf + boff + n * 512);
    if (t + 3 < NT) stageA((t + 3) & 3, (t + 3) * 32);
    __builtin_amdgcn_s_barrier();
    asm volatile("s_waitcnt lgkmcnt(0)" ::: "memory");
    __builtin_amdgcn_sched_barrier(0);
    __builtin_amdgcn_s_setprio(1);
#pragma unroll
    for (int i = 0; i < 4; i++)
#pragma unroll
      for (int n = 0; n < 4; n++)
        acc[i][n] = __builtin_amdgcn_mfma_f32_16x16x32_bf16(af[i], bfv[n], acc[i][n], 0, 0, 0);
    __builtin_amdgcn_s_setprio(0);
    __builtin_amdgcn_s_barrier();

    // ---- phase 2: m-half 1 ----
#pragma unroll
    for (int i = 0; i < 4; i++)
      af[i] = *(const bf16x8*)(Abuf + aoff + 2048 + i * 512);
    if (t + 3 < NT) stageB((t + 3) & 3, (t + 3) * 32);
    __builtin_amdgcn_s_barrier();
    asm volatile("s_waitcnt lgkmcnt(0)" ::: "memory");
    __builtin_amdgcn_sched_barrier(0);
    __builtin_amdgcn_s_setprio(1);
#pragma unroll
    for (int i = 0; i < 4; i++)
#pragma unroll
      for (int n = 0; n < 4; n++)
        acc[4 + i][n] = __builtin_amdgcn_mfma_f32_16x16x32_bf16(af[i], bfv[n], acc[4 + i][n], 0, 0, 0);
    __builtin_amdgcn_s_setprio(0);
    asm volatile("s_waitcnt vmcnt(8)" ::: "memory");  // tile t+1 fully resident
    __builtin_amdgcn_s_barrier();
  }

  // epilogue: C/D layout col=lane&15, row=(lane>>4)*4+r; planar KV split
  int rq = hi * 4;
#pragma unroll
  for (int i = 0; i < 8; i++) {
    long r0 = m0 + wr * 128 + i * 16 + rq;
#pragma unroll
    for (int n = 0; n < 4; n++) {
      int cc = n0 + wc * 64 + n * 16 + fr;
      float bsv = bias[cc];
      long p = (long)(cc >> 10) * plane + (cc & 1023);
#pragma unroll
      for (int r = 0; r < 4; r++)
        C[p + (r0 + r) * 1024] = f2bf(acc[i][n][r] + bsv);
    }
  }
}

// ---------------------------------------------------------------------------
// Host side
// ---------------------------------------------------------------------------
template <int TM, bool AF32, bool BIAS, int ACT, bool RES, bool OUTF, bool OUTB, bool KVSPLIT = false>
static void launch_gemm(hipStream_t s, int M, int N, int K, int nz, int zdiv,
                        const void* A, long a_off, int lda, long a_hi, long a_lo,
                        const unsigned short* B, long b_off, int ldb, long b_hi, long b_lo,
                        const float* bias, const float* Res,
                        float* Cf, long c_off, int ldc, long c_hi, long c_lo,
                        unsigned short* Cb, long cb_off, int ldcb, long cb_hi, long cb_lo) {
  dim3 g(M / TM, N / 128, nz);
  gemm_nt_kernel<TM, AF32, BIAS, ACT, RES, OUTF, OUTB, KVSPLIT><<<g, dim3(256), 0, s>>>(
      A, a_off, lda, a_hi, a_lo, B, b_off, ldb, b_hi, b_lo, bias, Res,
      Cf, c_off, ldc, c_hi, c_lo, Cb, cb_off, ldcb, cb_hi, cb_lo, K, zdiv);
}

// workspace layout (bytes). Weight regions 0..40MiB are CONTIGUOUS in cast order.
static const long WB_SAIN = 0;          // 6 MiB
static const long WB_SAOUT = 6291456;   // 2 MiB
static const long WB_WQ = 8388608;      // 2 MiB
static const long WB_WK = 10485760;     // 2 MiB  (wk||wv contiguous -> fused KV B)
static const long WB_WV = 12582912;     // 2 MiB
static const long WB_WO = 14680064;     // 2 MiB
static const long WB_W1 = 16777216;     // 8 MiB
static const long WB_W2 = 25165824;     // 8 MiB
static const long WB_MW = 33554432;     // 8 MiB
static const long OF_K = 41943040;      // 64 MiB: K planar; later V^T
static const long OF_V = 109051904;     // 64 MiB: V planar
static const long OF_QKV = 176160768;   // 12 MiB: qkv bf16; later x1 (fp32, 8 MiB)
static const long OF_BKV = 187695104;   // 8 KiB: concat [bk;bv]
static const long OF_SC = 188743680;    // 32 MiB: self-sc / cross-sc / x2 (fp32)
static const long OF_P = 222298112;     // 16 MiB: attn_p / attn2 / h (bf16)
static const long OF_QN = 239075328;    // 4 MiB: LN outs / self V^T (time-disjoint)
static const long OF_Q = 243269632;     // 4 MiB: Q proj
static const long OF_CTX = 247463936;   // 4 MiB: ctx / ctx2 / x3_bf  (end 251658240)
static const long OF_MEMBF = 251658240; // 64 MiB: memory cast to bf16 (fast path only)
static const size_t FAST_WS = 318767104;

extern "C" void kernel_launch(void* const* d_in, const int* in_sizes, int n_in,
                              void* d_out, int out_size, void* d_ws, size_t ws_size,
                              hipStream_t stream) {
  (void)in_sizes; (void)n_in; (void)out_size;
  const float* query = (const float*)d_in[0];
  const float* memoryp = (const float*)d_in[1];
  const float* prev_mask = (const float*)d_in[2];
  const float* sa_in_w = (const float*)d_in[5];
  const float* sa_in_b = (const float*)d_in[6];
  const float* sa_out_w = (const float*)d_in[7];
  const float* sa_out_b = (const float*)d_in[8];
  const float* ln1_g = (const float*)d_in[9], * ln1_b = (const float*)d_in[10];
  const float* ln2_g = (const float*)d_in[11], * ln2_b = (const float*)d_in[12];
  const float* ln3_g = (const float*)d_in[13], * ln3_b = (const float*)d_in[14];
  const float* wq = (const float*)d_in[15], * bq = (const float*)d_in[16];
  const float* wk = (const float*)d_in[17], * bk = (const float*)d_in[18];
  const float* wv = (const float*)d_in[19], * bv = (const float*)d_in[20];
  const float* wo = (const float*)d_in[21], * bo = (const float*)d_in[22];
  const float* w1 = (const float*)d_in[23], * b1 = (const float*)d_in[24];
  const float* w2 = (const float*)d_in[25], * b2 = (const float*)d_in[26];
  const float* mask_w = (const float*)d_in[27], * mask_b = (const float*)d_in[28];

  uint8_t* ws = (uint8_t*)d_ws;
  auto bf = [&](long off) { return (unsigned short*)(ws + off); };
  auto fp = [&](long off) { return (float*)(ws + off); };
  unsigned short* ZB = nullptr;
  float* ZF = nullptr;
  const bool fast = ws_size >= FAST_WS;

  // ---- all 9 weight casts in one launch (dst = ws[0..40MiB) contiguous) ----
  {
    CastSegs cs;
    const float* srcs[9] = {sa_in_w, sa_out_w, wq, wk, wv, wo, w1, w2, mask_w};
    int n8s[9] = {393216, 131072, 131072, 131072, 131072, 131072, 524288, 524288, 524288};
    int c = 0;
    for (int i = 0; i < 9; i++) { cs.src[i] = srcs[i]; cs.cum[i] = c; c += n8s[i]; }
    cs.cum[9] = c;  // 2621440
    cast_multi_kernel<<<dim3((c + 255) / 256), dim3(256), 0, stream>>>(cs, bf(0));
  }

  // ---- self attention ----
  ln_bf16_kernel<<<2048, 256, 0, stream>>>(query, ln1_g, ln1_b, bf(OF_QN));

  // qkv = qn @ sa_in_w^T + b  -> bf16 [2048 x 3072]
  launch_gemm<128, false, true, 0, false, false, true>(stream, 2048, 3072, 1024, 1, 1,
      bf(OF_QN), 0, 1024, 0, 0, bf(WB_SAIN), 0, 1024, 0, 0, sa_in_b, nullptr,
      ZF, 0, 0, 0, 0, bf(OF_QKV), 0, 3072, 0, 0);

  // self scores [b,h][256][256] fp32; z=(b*8+h)
  launch_gemm<128, false, false, 0, false, true, false>(stream, 256, 256, 128, 64, 8,
      bf(OF_QKV), 0, 24576, 3072, 128,
      bf(OF_QKV), 1024, 24576, 3072, 128, nullptr, nullptr,
      fp(OF_SC), 0, 256, 524288, 65536, ZB, 0, 0, 0, 0);

  softmax_bf16_kernel<false, 1><<<16384, 256, 0, stream>>>(
      fp(OF_SC), nullptr, bf(OF_P), 0.08838834764831845f);

  // self V^T: VT_s[z=(b*8+h)][d=128][s=256]
  transpose_bf16_kernel<<<dim3(4, 8, 64), 256, 0, stream>>>(
      bf(OF_QKV), bf(OF_QN), 2048L, 24576, 3072L, 128L, 8, 0L, 256, 262144L, 32768L);

  // ctx = attn_p @ VT_s^T  (TM=64 -> 256 blocks)
  launch_gemm<64, false, false, 0, false, false, true>(stream, 256, 128, 256, 64, 8,
      bf(OF_P), 0, 256, 524288, 65536,
      bf(OF_QN), 0, 256, 262144, 32768, nullptr, nullptr,
      ZF, 0, 0, 0, 0, bf(OF_CTX), 0, 8192, 1024, 128);

  // x1 = query + ctx @ sa_out_w^T + b -> fp32 at OF_QKV (TM=64)
  launch_gemm<64, false, true, 0, true, true, false>(stream, 2048, 1024, 1024, 1, 1,
      bf(OF_CTX), 0, 1024, 0, 0, bf(WB_SAOUT), 0, 1024, 0, 0, sa_out_b, query,
      fp(OF_QKV), 0, 1024, 0, 0, ZB, 0, 0, 0, 0);

  // ---- cross attention ----
  ln_bf16_kernel<<<2048, 256, 0, stream>>>(fp(OF_QKV), ln2_g, ln2_b, bf(OF_QN));

  launch_gemm<64, false, true, 0, false, false, true>(stream, 2048, 1024, 1024, 1, 1,
      bf(OF_QN), 0, 1024, 0, 0, bf(WB_WQ), 0, 1024, 0, 0, bq, nullptr,
      ZF, 0, 0, 0, 0, bf(OF_Q), 0, 1024, 0, 0);

  // fused K,V projection: [32768 x 2048] vs wk||wv, planar outputs K@OF_K, V@OF_V
  bias_concat_kernel<<<8, 256, 0, stream>>>(bk, bv, fp(OF_BKV));
  if (fast) {
    cast_bf16_kernel<<<16384, 256, 0, stream>>>(memoryp, bf(OF_MEMBF), 4194304);
    gemm256_kv_kernel<<<dim3(1024), dim3(512), 0, stream>>>(
        bf(OF_MEMBF), bf(WB_WK), fp(OF_BKV), bf(OF_K), 33554432L);
  } else {
    launch_gemm<128, true, true, 0, false, false, true, true>(stream, 32768, 2048, 1024, 1, 1,
        memoryp, 0, 1024, 0, 0, bf(WB_WK), 0, 1024, 0, 0, fp(OF_BKV), nullptr,
        ZF, 0, 0, 0, 0, bf(OF_K), 0, 1024, 33554432, 0);
  }

  // cross scores [b][256][4096] fp32
  launch_gemm<128, false, false, 0, false, true, false>(stream, 256, 4096, 1024, 8, 1,
      bf(OF_Q), 0, 8192, 1024, 0,
      bf(OF_K), 0, 8192, 1024, 0, nullptr, nullptr,
      fp(OF_SC), 0, 4096, 1048576, 0, ZB, 0, 0, 0, 0);

  softmax_bf16_kernel<true, 16><<<2048, 256, 0, stream>>>(
      fp(OF_SC), prev_mask, bf(OF_P), 0.03125f);

  // V^T[b][d=1024][s=4096] into OF_K region (K dead now)
  transpose_bf16_kernel<<<dim3(32, 128, 8), 256, 0, stream>>>(
      bf(OF_V), bf(OF_K), 0L, 8192, 1024L, 0L, 1, 0L, 4096, 4194304L, 0L);

  // ctx2 = attn2 @ VT^T (TM=64 -> 256 blocks)
  launch_gemm<64, false, false, 0, false, false, true>(stream, 256, 1024, 4096, 8, 1,
      bf(OF_P), 0, 4096, 1048576, 0,
      bf(OF_K), 0, 4096, 4194304, 0, nullptr, nullptr,
      ZF, 0, 0, 0, 0, bf(OF_CTX), 0, 8192, 1024, 0);

  // x2 = x1 + ctx2 @ wo^T + bo -> fp32 at OF_SC (TM=64)
  launch_gemm<64, false, true, 0, true, true, false>(stream, 2048, 1024, 1024, 1, 1,
      bf(OF_CTX), 0, 1024, 0, 0, bf(WB_WO), 0, 1024, 0, 0, bo, fp(OF_QKV),
      fp(OF_SC), 0, 1024, 0, 0, ZB, 0, 0, 0, 0);

  // ---- FFN ----
  ln_bf16_kernel<<<2048, 256, 0, stream>>>(fp(OF_SC), ln3_g, ln3_b, bf(OF_QN));

  // h = gelu(qn3 @ w1^T + b1) -> bf16 [2048 x 4096]
  launch_gemm<128, false, true, 1, false, false, true>(stream, 2048, 4096, 1024, 1, 1,
      bf(OF_QN), 0, 1024, 0, 0, bf(WB_W1), 0, 1024, 0, 0, b1, nullptr,
      ZF, 0, 0, 0, 0, bf(OF_P), 0, 4096, 0, 0);

  // x3 = x2 + h @ w2^T + b2 -> d_out (fp32) and bf16 copy (TM=64)
  launch_gemm<64, false, true, 0, true, true, true>(stream, 2048, 1024, 4096, 1, 1,
      bf(OF_P), 0, 4096, 0, 0, bf(WB_W2), 0, 4096, 0, 0, b2, fp(OF_SC),
      (float*)d_out, 0, 1024, 0, 0, bf(OF_CTX), 0, 1024, 0, 0);

  // pred_mask[b][q][4096] = sigmoid(x3 @ mask_w^T + mask_b)
  launch_gemm<128, false, true, 2, false, true, false>(stream, 256, 4096, 1024, 8, 1,
      bf(OF_CTX), 0, 8192, 1024, 0,
      bf(WB_MW), 0, 1024, 0, 0, mask_b, nullptr,
      (float*)d_out + 2097152, 0, 4096, 1048576, 0, ZB, 0, 0, 0, 0);
}

// Round 3
// 943.970 us; speedup vs baseline: 1.0641x; 1.0056x over previous
//
#include <hip/hip_runtime.h>
#include <cstdint>

// ---------------------------------------------------------------------------
// MaskedTransformerDecoderLayer on MI355X.
// All GEMMs: bf16-MFMA tiles (16x16x32), fp32 accumulate, double-buffered LDS.
// D=1024, NHEAD=8, NQ=256, B=8, S=4096, FF=4096.
// R3: KV-projection 256^2 kernel gets register-level ds-read pipelining:
// phase p+1's LDS fragments are read during phase p's MFMA (counted lgkmcnt,
// never 0 in-loop), buffer publish moved one phase early, 2 barriers/tile.
// ---------------------------------------------------------------------------

typedef __attribute__((ext_vector_type(8))) __bf16 bf16x8;
typedef __attribute__((ext_vector_type(4))) float f32x4;
typedef __attribute__((ext_vector_type(8))) unsigned short ushort8;
typedef __attribute__((ext_vector_type(4))) unsigned short ushort4v;

__device__ __forceinline__ unsigned short f2bf(float f) {
  return __builtin_bit_cast(unsigned short, (__bf16)f);
}

// ---------------- cast fp32 -> bf16 (8 elems/thread) ----------------
__global__ __launch_bounds__(256) void cast_bf16_kernel(const float* __restrict__ in,
                                                        unsigned short* __restrict__ out,
                                                        int n8) {
  int i = blockIdx.x * 256 + threadIdx.x;
  if (i >= n8) return;
  const float4* p = (const float4*)in + (size_t)i * 2;
  float4 a = p[0], b = p[1];
  ushort8 o;
  o[0] = f2bf(a.x); o[1] = f2bf(a.y); o[2] = f2bf(a.z); o[3] = f2bf(a.w);
  o[4] = f2bf(b.x); o[5] = f2bf(b.y); o[6] = f2bf(b.z); o[7] = f2bf(b.w);
  ((ushort8*)out)[i] = o;
}

// ---------------- fused multi-tensor cast (dst regions contiguous) ----------
struct CastSegs {
  const float* src[9];
  int cum[10];  // cumulative n8 counts
};
__global__ __launch_bounds__(256) void cast_multi_kernel(CastSegs cs,
                                                         unsigned short* __restrict__ out) {
  int i = blockIdx.x * 256 + threadIdx.x;
  if (i >= cs.cum[9]) return;
  int s = 0;
  while (i >= cs.cum[s + 1]) s++;
  const float4* p = (const float4*)cs.src[s] + (size_t)(i - cs.cum[s]) * 2;
  float4 a = p[0], b = p[1];
  ushort8 o;
  o[0] = f2bf(a.x); o[1] = f2bf(a.y); o[2] = f2bf(a.z); o[3] = f2bf(a.w);
  o[4] = f2bf(b.x); o[5] = f2bf(b.y); o[6] = f2bf(b.z); o[7] = f2bf(b.w);
  ((ushort8*)out)[i] = o;
}

__global__ __launch_bounds__(256) void bias_concat_kernel(const float* __restrict__ a,
                                                          const float* __restrict__ b,
                                                          float* __restrict__ o) {
  int i = blockIdx.x * 256 + threadIdx.x;
  o[i] = i < 1024 ? a[i] : b[i - 1024];
}

// ---------------- LayerNorm over D=1024, bf16 out ----------------
__global__ __launch_bounds__(256) void ln_bf16_kernel(const float* __restrict__ x,
                                                      const float* __restrict__ g,
                                                      const float* __restrict__ b,
                                                      unsigned short* __restrict__ out) {
  int row = blockIdx.x, tid = threadIdx.x;
  const float4* xr = (const float4*)(x + (size_t)row * 1024);
  float4 v = xr[tid];
  float s = v.x + v.y + v.z + v.w;
  float sq = v.x * v.x + v.y * v.y + v.z * v.z + v.w * v.w;
#pragma unroll
  for (int o = 32; o > 0; o >>= 1) { s += __shfl_xor(s, o); sq += __shfl_xor(sq, o); }
  __shared__ float red[8];
  int wave = tid >> 6, lane = tid & 63;
  if (lane == 0) { red[wave] = s; red[4 + wave] = sq; }
  __syncthreads();
  float ts = red[0] + red[1] + red[2] + red[3];
  float tq = red[4] + red[5] + red[6] + red[7];
  float mean = ts * (1.f / 1024.f);
  float var = tq * (1.f / 1024.f) - mean * mean;
  float rstd = rsqrtf(var + 1e-5f);
  float4 gv = ((const float4*)g)[tid];
  float4 bv = ((const float4*)b)[tid];
  ushort4v o;
  o[0] = f2bf((v.x - mean) * rstd * gv.x + bv.x);
  o[1] = f2bf((v.y - mean) * rstd * gv.y + bv.y);
  o[2] = f2bf((v.z - mean) * rstd * gv.z + bv.z);
  o[3] = f2bf((v.w - mean) * rstd * gv.w + bv.w);
  ((ushort4v*)(out + (size_t)row * 1024))[tid] = o;
}

// ---------------- rowwise softmax, optional +log(mask+1e-6), bf16 out -------
template <bool MASK, int CNT>
__global__ __launch_bounds__(256) void softmax_bf16_kernel(const float* __restrict__ sc,
                                                           const float* __restrict__ pm,
                                                           unsigned short* __restrict__ out,
                                                           float scale) {
  const int L = CNT * 256;
  int row = blockIdx.x, tid = threadIdx.x;
  const float* sr = sc + (size_t)row * L;
  float vals[CNT];
  float mx = -1e30f;
#pragma unroll
  for (int i = 0; i < CNT; i++) {
    int idx = tid + (i << 8);
    float v = sr[idx] * scale;
    if (MASK) v += __logf(pm[(size_t)row * L + idx] + 1e-6f);
    vals[i] = v;
    mx = fmaxf(mx, v);
  }
#pragma unroll
  for (int o = 32; o > 0; o >>= 1) mx = fmaxf(mx, __shfl_xor(mx, o));
  __shared__ float red[8];
  int wave = tid >> 6, lane = tid & 63;
  if (lane == 0) red[wave] = mx;
  __syncthreads();
  mx = fmaxf(fmaxf(red[0], red[1]), fmaxf(red[2], red[3]));
  float sum = 0.f;
#pragma unroll
  for (int i = 0; i < CNT; i++) { vals[i] = __expf(vals[i] - mx); sum += vals[i]; }
#pragma unroll
  for (int o = 32; o > 0; o >>= 1) sum += __shfl_xor(sum, o);
  if (lane == 0) red[4 + wave] = sum;
  __syncthreads();
  float rs = 1.f / (red[4] + red[5] + red[6] + red[7]);
#pragma unroll
  for (int i = 0; i < CNT; i++)
    out[(size_t)row * L + tid + (i << 8)] = f2bf(vals[i] * rs);
}

// ---------------- batched bf16 transpose (32x32 tiles via LDS) ----------------
__global__ __launch_bounds__(256) void transpose_bf16_kernel(
    const unsigned short* __restrict__ in, unsigned short* __restrict__ out,
    long in_off, int in_rs, long in_hi, long in_lo, int zdiv,
    long out_off, int out_rs, long out_hi, long out_lo) {
  __shared__ unsigned short t[32][33];
  int z = blockIdx.z;
  int zh = z / zdiv, zl = z % zdiv;
  const unsigned short* ib = in + in_off + (long)zh * in_hi + (long)zl * in_lo;
  unsigned short* ob = out + out_off + (long)zh * out_hi + (long)zl * out_lo;
  int i0 = blockIdx.x * 32;
  int j0 = blockIdx.y * 32;
  int tx = threadIdx.x & 31, ty = threadIdx.x >> 5;
#pragma unroll
  for (int r = ty; r < 32; r += 8) t[r][tx] = ib[(long)(j0 + r) * in_rs + i0 + tx];
  __syncthreads();
#pragma unroll
  for (int r = ty; r < 32; r += 8) ob[(long)(i0 + r) * out_rs + j0 + tx] = t[tx][r];
}

// ---------------- batched NT GEMM: C[m,n] = sum_k A[m,k]*B[n,k] ----------------
// Tile TM x 128, BK=32, 4 waves (2x2), DOUBLE-BUFFERED LDS.
template <int TM, bool AF32, bool BIAS, int ACT, bool RES, bool OUTF, bool OUTB, bool KVSPLIT>
__global__ __launch_bounds__(256) void gemm_nt_kernel(
    const void* __restrict__ Av, long a_off, int lda, long a_hi, long a_lo,
    const unsigned short* __restrict__ B, long b_off, int ldb, long b_hi, long b_lo,
    const float* __restrict__ bias, const float* __restrict__ Res,
    float* __restrict__ Cf, long c_off, int ldc, long c_hi, long c_lo,
    unsigned short* __restrict__ Cb, long cb_off, int ldcb, long cb_hi, long cb_lo,
    int K, int zdiv) {
  constexpr int MI = TM / 32;
  __shared__ unsigned short As[2 * TM * 32];
  __shared__ unsigned short Bs[2 * 128 * 32];
  int tid = threadIdx.x;
  int wave = tid >> 6, lane = tid & 63;
  int z = blockIdx.z, zh = z / zdiv, zl = z % zdiv;
  long m0 = (long)blockIdx.x * TM, n0 = (long)blockIdx.y * 128;

  const unsigned short* Bb = B + b_off + zh * b_hi + zl * b_lo + n0 * ldb;
  const unsigned short* Ab16 = nullptr;
  const float* Abf = nullptr;
  if constexpr (AF32)
    Abf = (const float*)Av + a_off + zh * a_hi + zl * a_lo + m0 * lda;
  else
    Ab16 = (const unsigned short*)Av + a_off + zh * a_hi + zl * a_lo + m0 * lda;

  int srow = lane >> 2;
  int scol = (lane & 3) * 8;
  int wm = (wave >> 1) * (TM / 2), wn = (wave & 1) * 64;
  int fr = lane & 15;
  int ko = (lane >> 4) * 8;

  f32x4 acc[MI][4] = {};

  auto stage = [&](int buf, int k0) {
    unsigned short* Ad = As + buf * (TM * 32);
    unsigned short* Bd = Bs + buf * (128 * 32);
    if constexpr (AF32) {
      int row = tid >> 1;
      int cs = (tid & 1) * 16;
      const float* ap = Abf + (long)row * lda + k0 + cs;
      float4 f0 = ((const float4*)ap)[0];
      float4 f1 = ((const float4*)ap)[1];
      float4 f2 = ((const float4*)ap)[2];
      float4 f3 = ((const float4*)ap)[3];
      ushort8 u0, u1;
      u0[0] = f2bf(f0.x); u0[1] = f2bf(f0.y); u0[2] = f2bf(f0.z); u0[3] = f2bf(f0.w);
      u0[4] = f2bf(f1.x); u0[5] = f2bf(f1.y); u0[6] = f2bf(f1.z); u0[7] = f2bf(f1.w);
      u1[0] = f2bf(f2.x); u1[1] = f2bf(f2.y); u1[2] = f2bf(f2.z); u1[3] = f2bf(f2.w);
      u1[4] = f2bf(f3.x); u1[5] = f2bf(f3.y); u1[6] = f2bf(f3.z); u1[7] = f2bf(f3.w);
      ushort8* dst = (ushort8*)(Ad + row * 32 + cs);
      dst[0] = u0;
      dst[1] = u1;
    } else {
#pragma unroll
      for (int is = 0; is < TM / 64; is++) {
        int rbase = wave * (TM / 4) + is * 16;
        const unsigned short* g = Ab16 + (long)(rbase + srow) * lda + k0 + scol;
        __builtin_amdgcn_global_load_lds(
            (const __attribute__((address_space(1))) unsigned int*)g,
            (__attribute__((address_space(3))) unsigned int*)(Ad + rbase * 32), 16, 0, 0);
      }
    }
#pragma unroll
    for (int is = 0; is < 2; is++) {
      int rbase = wave * 32 + is * 16;
      const unsigned short* g = Bb + (long)(rbase + srow) * ldb + k0 + scol;
      __builtin_amdgcn_global_load_lds(
          (const __attribute__((address_space(1))) unsigned int*)g,
          (__attribute__((address_space(3))) unsigned int*)(Bd + rbase * 32), 16, 0, 0);
    }
  };

  stage(0, 0);
  int cur = 0;
  for (int k0 = 0; k0 < K; k0 += 32, cur ^= 1) {
    __syncthreads();  // drains vmcnt: As/Bs[cur] ready; prev reads of [cur] done
    if (k0 + 32 < K) stage(cur ^ 1, k0 + 32);

    const unsigned short* Ar = As + cur * (TM * 32);
    const unsigned short* Br = Bs + cur * (128 * 32);
    bf16x8 af[MI], bfv[4];
#pragma unroll
    for (int i = 0; i < MI; i++)
      af[i] = *(const bf16x8*)(Ar + (wm + i * 16 + fr) * 32 + ko);
#pragma unroll
    for (int j = 0; j < 4; j++)
      bfv[j] = *(const bf16x8*)(Br + (wn + j * 16 + fr) * 32 + ko);
#pragma unroll
    for (int i = 0; i < MI; i++)
#pragma unroll
      for (int j = 0; j < 4; j++)
        acc[i][j] = __builtin_amdgcn_mfma_f32_16x16x32_bf16(af[i], bfv[j], acc[i][j], 0, 0, 0);
  }

  // epilogue: C/D layout col=lane&15, row=(lane>>4)*4+r
  long cfo = c_off + zh * c_hi + zl * c_lo;
  long cbo = cb_off + zh * cb_hi + zl * cb_lo;
  int rq = (lane >> 4) * 4;
#pragma unroll
  for (int i = 0; i < MI; i++) {
    long rbase = m0 + wm + i * 16 + rq;
#pragma unroll
    for (int j = 0; j < 4; j++) {
      long cc = n0 + wn + j * 16 + fr;
      float bsv = BIAS ? bias[cc] : 0.f;
      long p = KVSPLIT ? ((cc >> 10) * cb_hi + (cc & 1023)) : cc;
#pragma unroll
      for (int r = 0; r < 4; r++) {
        float v = acc[i][j][r] + bsv;
        long ro = rbase + r;
        if constexpr (RES) v += Res[cfo + ro * ldc + cc];
        if constexpr (ACT == 1) v = 0.5f * v * (1.f + erff(v * 0.7071067811865475f));
        if constexpr (ACT == 2) v = 1.f / (1.f + __expf(-v));
        if constexpr (OUTF) Cf[cfo + ro * ldc + cc] = v;
        if constexpr (OUTB) Cb[cbo + ro * ldcb + p] = f2bf(v);
      }
    }
  }
}

// ---------------------------------------------------------------------------
// 256x256-tile deep-pipelined NT GEMM, specialized for the KV projection:
//   A bf16 [32768][1024], B bf16 [2048][1024] (wk||wv), C bf16 planar KV split.
// 8 waves (2M x 4N), BK=32, 4 K-tile LDS buffers (4 x 32 KiB = 128 KiB).
//
// R3 SCHEDULE (register-level ds-read pipelining; NEW sync template, full
// ledger below). Registers: ping-pong sets P/Q for (afA[4],bfv[4]) + shared
// afB[4]. Tile t even->consumes P, odd->consumes Q.
//
// Tile t body (steady state, 2 barriers/tile):
//  PH1: issue 4 ds_reads afB   <- buf(t) m-rows [64,128) of wave half
//       stageA(buf(t+3))        [2 global_load_lds]
//       lgkmcnt(4)              -> retires the 8 reads (afA,bfv of t) issued
//                                  in PH2(t-1); the 4 afB stay outstanding
//       16 MFMA acc[0..3] += afA x bfv            (setprio 1..0)
//       vmcnt(N1)               -> retires tile t+1's 4 loads
//                                  N1 = 4*[t+2<NT] + 2*[t+3<NT] (6 steady)
//       s_barrier               -> publishes buffer t+1
//  PH2: issue 8 ds_reads (afA',bfv') <- buf(t+1)   [skip on final tile]
//       stageB(buf(t+3))
//       lgkmcnt(8)              -> retires the 4 afB reads (8 newer stay)
//                                  [final tile: lgkmcnt(0)]
//       16 MFMA acc[4..7] += afB x bfv            (setprio 1..0)
//       s_barrier
//
// vmcnt ledger (in-order retire; 4 loads/tile/wave, stageA in PH1, stageB in
// PH2 of tile t stage tile t+3): before PH1(t) vmcnt: outstanding =
// t+1(4) + t+2(4) + t+3A(2) = 10 -> vmcnt(6) retires t+1. Tails: t=29 ->
// outstanding 8, vmcnt(4); t=30 -> outstanding 4, vmcnt(0); t=31 none.
// lgkmcnt ledger: PH1 wait: 8 old + 4 new = 12 -> lgkmcnt(4); PH2 wait:
// 4 old + 8 new = 12 -> lgkmcnt(8); final tile PH2: lgkmcnt(0).
// WAR audit: buffer b=t&3 rewritten (for tile t+4) by stageA at PH1(t+1),
// after PH2(t)'s trailing barrier, by which point every wave's afB reads of
// buf(t) completed (own lgkmcnt(8) in PH2(t)). Reads of buf(t+1) in PH2(t)
// occur after PH1(t)'s vmcnt+barrier publish. Prologue stages tiles 0-2,
// vmcnt(8) retires tile 0, barrier, then reads (afA,bfv) of tile 0 into P.
//
// LDS st-swizzle unchanged from R1/R2 (verified): linear global_load_lds dest
// + inverse-swz global source col + swz ds_read addr (rule #21).
// Grid remap unchanged from R2 (FETCH near-ideal).
// ---------------------------------------------------------------------------
#define KV_TILE(T, AFA, BFV, AFAN, BFVN, VM1, LG2, DOSTAGE, DONEXT)            \
  {                                                                            \
    const unsigned short* Abuf = &lds[(T) & 3][0][0];                          \
    const unsigned short* AbufN = &lds[((T) + 1) & 3][0][0];                   \
    const unsigned short* BbufN = &lds[((T) + 1) & 3][1][0];                   \
    _Pragma("unroll") for (int i = 0; i < 4; i++)                              \
        afB[i] = *(const bf16x8*)(Abuf + aoff + 2048 + i * 512);               \
    if (DOSTAGE) stageA(((T) + 3) & 3, ((T) + 3) * 32);                        \
    __builtin_amdgcn_sched_barrier(0);                                         \
    asm volatile("s_waitcnt lgkmcnt(4)" ::: "memory");                         \
    __builtin_amdgcn_sched_barrier(0);                                         \
    __builtin_amdgcn_s_setprio(1);                                             \
    _Pragma("unroll") for (int i = 0; i < 4; i++)                              \
        _Pragma("unroll") for (int n = 0; n < 4; n++)                          \
            acc[i][n] = __builtin_amdgcn_mfma_f32_16x16x32_bf16(               \
                AFA[i], BFV[n], acc[i][n], 0, 0, 0);                           \
    __builtin_amdgcn_s_setprio(0);                                             \
    asm volatile("s_waitcnt vmcnt(" #VM1 ")" ::: "memory");                    \
    __builtin_amdgcn_s_barrier();                                              \
    if (DONEXT) {                                                              \
      _Pragma("unroll") for (int i = 0; i < 4; i++)                            \
          AFAN[i] = *(const bf16x8*)(AbufN + aoff + i * 512);                  \
      _Pragma("unroll") for (int n = 0; n < 4; n++)                            \
          BFVN[n] = *(const bf16x8*)(BbufN + boff + n * 512);                  \
    }                                                                          \
    if (DOSTAGE) stageB(((T) + 3) & 3, ((T) + 3) * 32);                        \
    __builtin_amdgcn_sched_barrier(0);                                         \
    asm volatile("s_waitcnt lgkmcnt(" #LG2 ")" ::: "memory");                  \
    __builtin_amdgcn_sched_barrier(0);                                         \
    __builtin_amdgcn_s_setprio(1);                                             \
    _Pragma("unroll") for (int i = 0; i < 4; i++)                              \
        _Pragma("unroll") for (int n = 0; n < 4; n++)                          \
            acc[4 + i][n] = __builtin_amdgcn_mfma_f32_16x16x32_bf16(           \
                afB[i], BFV[n], acc[4 + i][n], 0, 0, 0);                       \
    __builtin_amdgcn_s_setprio(0);                                             \
    __builtin_amdgcn_s_barrier();                                              \
  }

__global__ __launch_bounds__(512) void gemm256_kv_kernel(
    const unsigned short* __restrict__ A,   // [32768][1024] bf16
    const unsigned short* __restrict__ B,   // [2048][1024] bf16 (wk||wv)
    const float* __restrict__ bias,         // [2048] (bk||bv)
    unsigned short* __restrict__ C,         // K plane; V plane at +plane elems
    long plane) {
  __shared__ __align__(1024) unsigned short lds[4][2][8192];  // [buf][A/B][256*32]
  const int K = 1024, NT = 32;
  int tid = threadIdx.x;
  int wave = tid >> 6, lane = tid & 63;
  int wr = wave >> 2, wc = wave & 3;
  int fr = lane & 15, hi = lane >> 4;

  // L2-locality remap (bijective: 1024 wgs, 1024%8==0). XCD owns an m-chunk.
  int l = blockIdx.x >> 3;
  long m0 = (long)((blockIdx.x & 7) * 16 + (l >> 3)) * 256;
  int n0 = (l & 7) * 256;

  const unsigned short* Ab = A + m0 * K;
  const unsigned short* Bb = B + (long)n0 * K;

  // staging: per wave per tile, 4 x global_load_lds of 1KiB segments.
  int lr = lane >> 2;
  int lc = (((lane & 3) ^ ((lane >> 5) << 1)) << 3);  // inverse-swz source col

  auto stageA = [&](int buf, int k0) {
    const unsigned short* g0 = Ab + (long)(wave * 16 + lr) * K + k0 + lc;
    __builtin_amdgcn_global_load_lds(
        (const __attribute__((address_space(1))) unsigned int*)g0,
        (__attribute__((address_space(3))) unsigned int*)&lds[buf][0][wave * 512], 16, 0, 0);
    const unsigned short* g1 = g0 + (long)128 * K;
    __builtin_amdgcn_global_load_lds(
        (const __attribute__((address_space(1))) unsigned int*)g1,
        (__attribute__((address_space(3))) unsigned int*)&lds[buf][0][4096 + wave * 512], 16, 0, 0);
  };
  auto stageB = [&](int buf, int k0) {
    const unsigned short* g0 = Bb + (long)(wave * 16 + lr) * K + k0 + lc;
    __builtin_amdgcn_global_load_lds(
        (const __attribute__((address_space(1))) unsigned int*)g0,
        (__attribute__((address_space(3))) unsigned int*)&lds[buf][1][wave * 512], 16, 0, 0);
    const unsigned short* g1 = g0 + (long)128 * K;
    __builtin_amdgcn_global_load_lds(
        (const __attribute__((address_space(1))) unsigned int*)g1,
        (__attribute__((address_space(3))) unsigned int*)&lds[buf][1][4096 + wave * 512], 16, 0, 0);
  };

  // read-side swizzled column (elements)
  int cbel = ((hi * 16) ^ ((fr >> 3) << 5)) >> 1;
  int aoff = (wr * 128 + fr) * 32 + cbel;
  int boff = (wc * 64 + fr) * 32 + cbel;

  f32x4 acc[8][4] = {};
  bf16x8 afA_p[4], bfv_p[4], afA_q[4], bfv_q[4], afB[4];

  // prologue: stage tiles 0,1,2; retire tile 0; publish; read tile-0 frags.
#pragma unroll
  for (int t = 0; t < 3; t++) { stageA(t, t * 32); stageB(t, t * 32); }
  asm volatile("s_waitcnt vmcnt(8)" ::: "memory");
  __builtin_amdgcn_s_barrier();
  {
    const unsigned short* Abuf0 = &lds[0][0][0];
    const unsigned short* Bbuf0 = &lds[0][1][0];
#pragma unroll
    for (int i = 0; i < 4; i++) afA_p[i] = *(const bf16x8*)(Abuf0 + aoff + i * 512);
#pragma unroll
    for (int n = 0; n < 4; n++) bfv_p[n] = *(const bf16x8*)(Bbuf0 + boff + n * 512);
  }

  for (int t = 0; t < 28; t += 2) {
    KV_TILE(t, afA_p, bfv_p, afA_q, bfv_q, 6, 8, 1, 1)
    KV_TILE(t + 1, afA_q, bfv_q, afA_p, bfv_p, 6, 8, 1, 1)
  }
  KV_TILE(28, afA_p, bfv_p, afA_q, bfv_q, 6, 8, 1, 1)
  KV_TILE(29, afA_q, bfv_q, afA_p, bfv_p, 4, 8, 0, 1)
  KV_TILE(30, afA_p, bfv_p, afA_q, bfv_q, 0, 8, 0, 1)
  KV_TILE(31, afA_q, bfv_q, afA_p, bfv_p, 0, 0, 0, 0)

  // epilogue: C/D layout col=lane&15, row=(lane>>4)*4+r; planar KV split
  int rq = hi * 4;
#pragma unroll
  for (int i = 0; i < 8; i++) {
    long r0 = m0 + wr * 128 + i * 16 + rq;
#pragma unroll
    for (int n = 0; n < 4; n++) {
      int cc = n0 + wc * 64 + n * 16 + fr;
      float bsv = bias[cc];
      long p = (long)(cc >> 10) * plane + (cc & 1023);
#pragma unroll
      for (int r = 0; r < 4; r++)
        C[p + (r0 + r) * 1024] = f2bf(acc[i][n][r] + bsv);
    }
  }
}

// ---------------------------------------------------------------------------
// Host side
// ---------------------------------------------------------------------------
template <int TM, bool AF32, bool BIAS, int ACT, bool RES, bool OUTF, bool OUTB, bool KVSPLIT = false>
static void launch_gemm(hipStream_t s, int M, int N, int K, int nz, int zdiv,
                        const void* A, long a_off, int lda, long a_hi, long a_lo,
                        const unsigned short* B, long b_off, int ldb, long b_hi, long b_lo,
                        const float* bias, const float* Res,
                        float* Cf, long c_off, int ldc, long c_hi, long c_lo,
                        unsigned short* Cb, long cb_off, int ldcb, long cb_hi, long cb_lo) {
  dim3 g(M / TM, N / 128, nz);
  gemm_nt_kernel<TM, AF32, BIAS, ACT, RES, OUTF, OUTB, KVSPLIT><<<g, dim3(256), 0, s>>>(
      A, a_off, lda, a_hi, a_lo, B, b_off, ldb, b_hi, b_lo, bias, Res,
      Cf, c_off, ldc, c_hi, c_lo, Cb, cb_off, ldcb, cb_hi, cb_lo, K, zdiv);
}

// workspace layout (bytes). Weight regions 0..40MiB are CONTIGUOUS in cast order.
static const long WB_SAIN = 0;          // 6 MiB
static const long WB_SAOUT = 6291456;   // 2 MiB
static const long WB_WQ = 8388608;      // 2 MiB
static const long WB_WK = 10485760;     // 2 MiB  (wk||wv contiguous -> fused KV B)
static const long WB_WV = 12582912;     // 2 MiB
static const long WB_WO = 14680064;     // 2 MiB
static const long WB_W1 = 16777216;     // 8 MiB
static const long WB_W2 = 25165824;     // 8 MiB
static const long WB_MW = 33554432;     // 8 MiB
static const long OF_K = 41943040;      // 64 MiB: K planar; later V^T
static const long OF_V = 109051904;     // 64 MiB: V planar
static const long OF_QKV = 176160768;   // 12 MiB: qkv bf16; later x1 (fp32, 8 MiB)
static const long OF_BKV = 187695104;   // 8 KiB: concat [bk;bv]
static const long OF_SC = 188743680;    // 32 MiB: self-sc / cross-sc / x2 (fp32)
static const long OF_P = 222298112;     // 16 MiB: attn_p / attn2 / h (bf16)
static const long OF_QN = 239075328;    // 4 MiB: LN outs / self V^T (time-disjoint)
static const long OF_Q = 243269632;     // 4 MiB: Q proj
static const long OF_CTX = 247463936;   // 4 MiB: ctx / ctx2 / x3_bf  (end 251658240)
static const long OF_MEMBF = 251658240; // 64 MiB: memory cast to bf16 (fast path only)
static const size_t FAST_WS = 318767104;

extern "C" void kernel_launch(void* const* d_in, const int* in_sizes, int n_in,
                              void* d_out, int out_size, void* d_ws, size_t ws_size,
                              hipStream_t stream) {
  (void)in_sizes; (void)n_in; (void)out_size;
  const float* query = (const float*)d_in[0];
  const float* memoryp = (const float*)d_in[1];
  const float* prev_mask = (const float*)d_in[2];
  const float* sa_in_w = (const float*)d_in[5];
  const float* sa_in_b = (const float*)d_in[6];
  const float* sa_out_w = (const float*)d_in[7];
  const float* sa_out_b = (const float*)d_in[8];
  const float* ln1_g = (const float*)d_in[9], * ln1_b = (const float*)d_in[10];
  const float* ln2_g = (const float*)d_in[11], * ln2_b = (const float*)d_in[12];
  const float* ln3_g = (const float*)d_in[13], * ln3_b = (const float*)d_in[14];
  const float* wq = (const float*)d_in[15], * bq = (const float*)d_in[16];
  const float* wk = (const float*)d_in[17], * bk = (const float*)d_in[18];
  const float* wv = (const float*)d_in[19], * bv = (const float*)d_in[20];
  const float* wo = (const float*)d_in[21], * bo = (const float*)d_in[22];
  const float* w1 = (const float*)d_in[23], * b1 = (const float*)d_in[24];
  const float* w2 = (const float*)d_in[25], * b2 = (const float*)d_in[26];
  const float* mask_w = (const float*)d_in[27], * mask_b = (const float*)d_in[28];

  uint8_t* ws = (uint8_t*)d_ws;
  auto bf = [&](long off) { return (unsigned short*)(ws + off); };
  auto fp = [&](long off) { return (float*)(ws + off); };
  unsigned short* ZB = nullptr;
  float* ZF = nullptr;
  const bool fast = ws_size >= FAST_WS;

  // ---- all 9 weight casts in one launch (dst = ws[0..40MiB) contiguous) ----
  {
    CastSegs cs;
    const float* srcs[9] = {sa_in_w, sa_out_w, wq, wk, wv, wo, w1, w2, mask_w};
    int n8s[9] = {393216, 131072, 131072, 131072, 131072, 131072, 524288, 524288, 524288};
    int c = 0;
    for (int i = 0; i < 9; i++) { cs.src[i] = srcs[i]; cs.cum[i] = c; c += n8s[i]; }
    cs.cum[9] = c;  // 2621440
    cast_multi_kernel<<<dim3((c + 255) / 256), dim3(256), 0, stream>>>(cs, bf(0));
  }

  // ---- self attention ----
  ln_bf16_kernel<<<2048, 256, 0, stream>>>(query, ln1_g, ln1_b, bf(OF_QN));

  // qkv = qn @ sa_in_w^T + b  -> bf16 [2048 x 3072]
  launch_gemm<128, false, true, 0, false, false, true>(stream, 2048, 3072, 1024, 1, 1,
      bf(OF_QN), 0, 1024, 0, 0, bf(WB_SAIN), 0, 1024, 0, 0, sa_in_b, nullptr,
      ZF, 0, 0, 0, 0, bf(OF_QKV), 0, 3072, 0, 0);

  // self scores [b,h][256][256] fp32; z=(b*8+h)
  launch_gemm<128, false, false, 0, false, true, false>(stream, 256, 256, 128, 64, 8,
      bf(OF_QKV), 0, 24576, 3072, 128,
      bf(OF_QKV), 1024, 24576, 3072, 128, nullptr, nullptr,
      fp(OF_SC), 0, 256, 524288, 65536, ZB, 0, 0, 0, 0);

  softmax_bf16_kernel<false, 1><<<16384, 256, 0, stream>>>(
      fp(OF_SC), nullptr, bf(OF_P), 0.08838834764831845f);

  // self V^T: VT_s[z=(b*8+h)][d=128][s=256]
  transpose_bf16_kernel<<<dim3(4, 8, 64), 256, 0, stream>>>(
      bf(OF_QKV), bf(OF_QN), 2048L, 24576, 3072L, 128L, 8, 0L, 256, 262144L, 32768L);

  // ctx = attn_p @ VT_s^T  (TM=64 -> 256 blocks)
  launch_gemm<64, false, false, 0, false, false, true>(stream, 256, 128, 256, 64, 8,
      bf(OF_P), 0, 256, 524288, 65536,
      bf(OF_QN), 0, 256, 262144, 32768, nullptr, nullptr,
      ZF, 0, 0, 0, 0, bf(OF_CTX), 0, 8192, 1024, 128);

  // x1 = query + ctx @ sa_out_w^T + b -> fp32 at OF_QKV (TM=64)
  launch_gemm<64, false, true, 0, true, true, false>(stream, 2048, 1024, 1024, 1, 1,
      bf(OF_CTX), 0, 1024, 0, 0, bf(WB_SAOUT), 0, 1024, 0, 0, sa_out_b, query,
      fp(OF_QKV), 0, 1024, 0, 0, ZB, 0, 0, 0, 0);

  // ---- cross attention ----
  ln_bf16_kernel<<<2048, 256, 0, stream>>>(fp(OF_QKV), ln2_g, ln2_b, bf(OF_QN));

  launch_gemm<64, false, true, 0, false, false, true>(stream, 2048, 1024, 1024, 1, 1,
      bf(OF_QN), 0, 1024, 0, 0, bf(WB_WQ), 0, 1024, 0, 0, bq, nullptr,
      ZF, 0, 0, 0, 0, bf(OF_Q), 0, 1024, 0, 0);

  // fused K,V projection: [32768 x 2048] vs wk||wv, planar outputs K@OF_K, V@OF_V
  bias_concat_kernel<<<8, 256, 0, stream>>>(bk, bv, fp(OF_BKV));
  if (fast) {
    cast_bf16_kernel<<<16384, 256, 0, stream>>>(memoryp, bf(OF_MEMBF), 4194304);
    gemm256_kv_kernel<<<dim3(1024), dim3(512), 0, stream>>>(
        bf(OF_MEMBF), bf(WB_WK), fp(OF_BKV), bf(OF_K), 33554432L);
  } else {
    launch_gemm<128, true, true, 0, false, false, true, true>(stream, 32768, 2048, 1024, 1, 1,
        memoryp, 0, 1024, 0, 0, bf(WB_WK), 0, 1024, 0, 0, fp(OF_BKV), nullptr,
        ZF, 0, 0, 0, 0, bf(OF_K), 0, 1024, 33554432, 0);
  }

  // cross scores [b][256][4096] fp32
  launch_gemm<128, false, false, 0, false, true, false>(stream, 256, 4096, 1024, 8, 1,
      bf(OF_Q), 0, 8192, 1024, 0,
      bf(OF_K), 0, 8192, 1024, 0, nullptr, nullptr,
      fp(OF_SC), 0, 4096, 1048576, 0, ZB, 0, 0, 0, 0);

  softmax_bf16_kernel<true, 16><<<2048, 256, 0, stream>>>(
      fp(OF_SC), prev_mask, bf(OF_P), 0.03125f);

  // V^T[b][d=1024][s=4096] into OF_K region (K dead now)
  transpose_bf16_kernel<<<dim3(32, 128, 8), 256, 0, stream>>>(
      bf(OF_V), bf(OF_K), 0L, 8192, 1024L, 0L, 1, 0L, 4096, 4194304L, 0L);

  // ctx2 = attn2 @ VT^T (TM=64 -> 256 blocks)
  launch_gemm<64, false, false, 0, false, false, true>(stream, 256, 1024, 4096, 8, 1,
      bf(OF_P), 0, 4096, 1048576, 0,
      bf(OF_K), 0, 4096, 4194304, 0, nullptr, nullptr,
      ZF, 0, 0, 0, 0, bf(OF_CTX), 0, 8192, 1024, 0);

  // x2 = x1 + ctx2 @ wo^T + bo -> fp32 at OF_SC (TM=64)
  launch_gemm<64, false, true, 0, true, true, false>(stream, 2048, 1024, 1024, 1, 1,
      bf(OF_CTX), 0, 1024, 0, 0, bf(WB_WO), 0, 1024, 0, 0, bo, fp(OF_QKV),
      fp(OF_SC), 0, 1024, 0, 0, ZB, 0, 0, 0, 0);

  // ---- FFN ----
  ln_bf16_kernel<<<2048, 256, 0, stream>>>(fp(OF_SC), ln3_g, ln3_b, bf(OF_QN));

  // h = gelu(qn3 @ w1^T + b1) -> bf16 [2048 x 4096]
  launch_gemm<128, false, true, 1, false, false, true>(stream, 2048, 4096, 1024, 1, 1,
      bf(OF_QN), 0, 1024, 0, 0, bf(WB_W1), 0, 1024, 0, 0, b1, nullptr,
      ZF, 0, 0, 0, 0, bf(OF_P), 0, 4096, 0, 0);

  // x3 = x2 + h @ w2^T + b2 -> d_out (fp32) and bf16 copy (TM=64)
  launch_gemm<64, false, true, 0, true, true, true>(stream, 2048, 1024, 4096, 1, 1,
      bf(OF_P), 0, 4096, 0, 0, bf(WB_W2), 0, 4096, 0, 0, b2, fp(OF_SC),
      (float*)d_out, 0, 1024, 0, 0, bf(OF_CTX), 0, 1024, 0, 0);

  // pred_mask[b][q][4096] = sigmoid(x3 @ mask_w^T + mask_b)
  launch_gemm<128, false, true, 2, false, true, false>(stream, 256, 4096, 1024, 8, 1,
      bf(OF_CTX), 0, 8192, 1024, 0,
      bf(WB_MW), 0, 1024, 0, 0, mask_b, nullptr,
      (float*)d_out + 2097152, 0, 4096, 1048576, 0, ZB, 0, 0, 0, 0);
}